// Round 2
// baseline (3295.505 us; speedup 1.0000x reference)
//
#include <hip/hip_runtime.h>
#include <hip/hip_bf16.h>
#include <math.h>

typedef __hip_bfloat16 bf16;

// ---------------- problem constants ----------------
constexpr int CB   = 2;            // batch
constexpr int CH   = 224, CW = 224;
constexpr int NHW  = 56;           // H/WS
constexpr int NPATCH = CB * NHW * NHW;   // 6272
constexpr int TOKPB  = CH * CW;          // 50176 tokens per batch
constexpr int MTOK   = CB * TOKPB;       // 100352 rows

// ---------------- ws layout (BYTE offsets) ----------------
// bf16 pools
constexpr size_t B_T0  = 0;                         // 19267584 bf16 = 38,535,168 B
constexpr size_t B_P2  = B_T0 + 38535168;           // 57802752 bf16 = 115,605,504 B (QKV; later HID)
constexpr size_t B_P3  = B_P2 + 115605504;          // 19267584 bf16 (XN -> ATT -> XM)
constexpr size_t B_P4  = B_P3 + 38535168;           // 19267584 bf16 (OMID)
constexpr size_t B_W1T = B_P4 + 38535168;           // 331776 f32
constexpr size_t B_W2T = B_W1T + 1327104;           // 331776 f32
constexpr size_t B_W3T = B_W2T + 1327104;           // 36864 f32
constexpr size_t WS_NEEDED = B_W3T + 147456;        // 234,012,672 B  (~223.2 MiB)

// ---------------- type helpers ----------------
__device__ __forceinline__ float ldf(const float* p) { return *p; }
__device__ __forceinline__ float ldf(const bf16* p)  { return __bfloat162float(*p); }
__device__ __forceinline__ void  stf(float* p, float v) { *p = v; }
__device__ __forceinline__ void  stf(bf16* p, float v)  { *p = __float2bfloat16(v); }

// ---------------- weight transposes ----------------
__global__ void transpose_w_kernel(const float* __restrict__ w, float* __restrict__ wt) {
    int o = blockIdx.x * 256 + threadIdx.x;
    if (o >= 192 * 192 * 9) return;
    int ci9 = o / 192, co = o % 192;     // wt[(ci*9+k)*192 + co]
    int ci = ci9 / 9, k = ci9 % 9;
    wt[o] = w[(co * 192 + ci) * 9 + k];
}
__global__ void transpose_w3_kernel(const float* __restrict__ w, float* __restrict__ wt) {
    int o = blockIdx.x * 256 + threadIdx.x;
    if (o >= 192 * 192) return;
    int ci = o / 192, co = o % 192;      // wt[ci*192+co]
    wt[o] = w[co * 192 + ci];
}

// ---------------- conv3x3 on 4x4 patches + groupnorm (+silu) ----------------
// FIRST=true : src = x flat (patch n = flat range n*3072..), dst = token layout (b,t,c) bf16, SiLU
// FIRST=false: src = token layout f32 (d_out), dst = flat layout f32 (d_out, in-place safe)
template <bool FIRST, typename TS, typename TD>
__global__ __launch_bounds__(192) void conv_gn_kernel(
    const TS* __restrict__ src, const float* __restrict__ wt,
    const float* __restrict__ bias, const float* __restrict__ gng,
    const float* __restrict__ gnb, TD* __restrict__ dst)
{
    __shared__ float sm[16 * 193];     // [pos][ci], stride 193
    __shared__ float reds[192], reds2[192];
    __shared__ float gstat[12];        // mu[6], rs[6]
    const int n   = blockIdx.x;
    const int tid = threadIdx.x;
    const int b   = n / (NHW * NHW);
    const int tb  = (n % (NHW * NHW)) * 16;

    if (FIRST) {
        const TS* sp = src + (size_t)n * 3072;
        for (int u = 0; u < 16; ++u) {
            int li = tid + u * 192;              // li = ci*16 + p
            sm[(li & 15) * 193 + (li >> 4)] = ldf(&sp[li]);
        }
    } else {
        for (int u = 0; u < 16; ++u) {           // p = u, ci = tid
            sm[u * 193 + tid] = ldf(&src[((size_t)(b * TOKPB + tb + u)) * 192 + tid]);
        }
    }
    __syncthreads();

    const int co = tid;
    float acc[16];
    {
        float bv = bias[co];
        #pragma unroll
        for (int p = 0; p < 16; ++p) acc[p] = bv;
    }
    for (int ci = 0; ci < 192; ++ci) {
        float wr[9];
        #pragma unroll
        for (int k = 0; k < 9; ++k) wr[k] = wt[(ci * 9 + k) * 192 + co];
        float xv[16];
        #pragma unroll
        for (int p = 0; p < 16; ++p) xv[p] = sm[p * 193 + ci];
        #pragma unroll
        for (int p = 0; p < 16; ++p) {
            const int i = p >> 2, j = p & 3;
            float a = acc[p];
            #pragma unroll
            for (int di = 0; di < 3; ++di) {
                const int ii = i + di - 1;
                if (ii < 0 || ii > 3) continue;
                #pragma unroll
                for (int dj = 0; dj < 3; ++dj) {
                    const int jj = j + dj - 1;
                    if (jj < 0 || jj > 3) continue;
                    a += xv[ii * 4 + jj] * wr[di * 3 + dj];
                }
            }
            acc[p] = a;
        }
    }

    // group stats: group g = co/32, 32 ch * 16 pos = 512 vals
    float s = 0.f, s2 = 0.f;
    #pragma unroll
    for (int p = 0; p < 16; ++p) { s += acc[p]; s2 += acc[p] * acc[p]; }
    reds[co] = s; reds2[co] = s2;
    __syncthreads();
    if (tid < 6) {
        float gs = 0.f, gs2 = 0.f;
        for (int c = tid * 32; c < tid * 32 + 32; ++c) { gs += reds[c]; gs2 += reds2[c]; }
        float mu  = gs * (1.f / 512.f);
        float var = gs2 * (1.f / 512.f) - mu * mu;
        gstat[tid]     = mu;
        gstat[6 + tid] = rsqrtf(var + 1e-5f);
    }
    __syncthreads();
    const int g = co >> 5;
    const float mu = gstat[g], rs = gstat[6 + g];
    const float gg = gng[co], gb = gnb[co];

    if (FIRST) {
        #pragma unroll
        for (int p = 0; p < 16; ++p) {
            float v = (acc[p] - mu) * rs * gg + gb;
            v = v / (1.f + expf(-v));            // silu
            stf(&dst[((size_t)(b * TOKPB + tb + p)) * 192 + co], v);
        }
    } else {
        #pragma unroll
        for (int p = 0; p < 16; ++p) {
            sm[p * 193 + co] = (acc[p] - mu) * rs * gg + gb;
        }
        __syncthreads();
        TD* dp = dst + (size_t)n * 3072;
        for (int u = 0; u < 16; ++u) {
            int li = tid + u * 192;              // li = ci*16 + p (flat within patch)
            stf(&dp[li], sm[(li & 15) * 193 + (li >> 4)]);
        }
    }
}

// ---------------- layernorm over last dim (192), bf16 -> bf16 ----------------
__global__ __launch_bounds__(256) void ln_kernel(
    const bf16* __restrict__ in, const float* __restrict__ g,
    const float* __restrict__ bb, bf16* __restrict__ out)
{
    const int row  = blockIdx.x * 4 + (threadIdx.x >> 6);
    const int lane = threadIdx.x & 63;
    const bf16* ip = in + (size_t)row * 192;
    float v0 = ldf(&ip[lane]), v1 = ldf(&ip[lane + 64]), v2 = ldf(&ip[lane + 128]);
    float s = v0 + v1 + v2, s2 = v0 * v0 + v1 * v1 + v2 * v2;
    #pragma unroll
    for (int off = 32; off; off >>= 1) { s += __shfl_xor(s, off); s2 += __shfl_xor(s2, off); }
    const float mu  = s * (1.f / 192.f);
    const float var = s2 * (1.f / 192.f) - mu * mu;
    const float rs  = rsqrtf(var + 1e-5f);
    bf16* op = out + (size_t)row * 192;
    stf(&op[lane],       (v0 - mu) * rs * g[lane]       + bb[lane]);
    stf(&op[lane + 64],  (v1 - mu) * rs * g[lane + 64]  + bb[lane + 64]);
    stf(&op[lane + 128], (v2 - mu) * rs * g[lane + 128] + bb[lane + 128]);
}

// ---------------- generic tiled GEMM: out = A(MxK) @ B(KxN) + bias (+res) (+gelu) ----------------
// A: TA (bf16), Bw/bias: f32, res: bf16, out: TO
template <typename TA, typename TO, bool RES, bool GELU_ACT>
__global__ __launch_bounds__(256) void gemm_kernel(
    const TA* __restrict__ A, const float* __restrict__ Bw,
    const float* __restrict__ bias, const bf16* __restrict__ res,
    TO* __restrict__ out, int K, int N)
{
    __shared__ float As[32][68];
    __shared__ float Bs[32][64];
    const int m0 = blockIdx.x * 64;
    const int n0 = blockIdx.y * 64;
    const int tid = threadIdx.x;
    const int tx = tid & 15, ty = tid >> 4;
    float acc[4][4] = {};

    for (int k0 = 0; k0 < K; k0 += 32) {
        #pragma unroll
        for (int u = 0; u < 8; ++u) {
            int li = tid + u * 256;
            int r = li >> 5, kk = li & 31;
            As[kk][r] = ldf(&A[(size_t)(m0 + r) * K + k0 + kk]);
        }
        #pragma unroll
        for (int u = 0; u < 8; ++u) {
            int li = tid + u * 256;
            int kk = li >> 6, c = li & 63;
            Bs[kk][c] = Bw[(size_t)(k0 + kk) * N + n0 + c];
        }
        __syncthreads();
        #pragma unroll
        for (int kk = 0; kk < 32; ++kk) {
            float4 av = *(const float4*)&As[kk][ty * 4];
            float4 bv = *(const float4*)&Bs[kk][tx * 4];
            float a_[4] = { av.x, av.y, av.z, av.w };
            float b_[4] = { bv.x, bv.y, bv.z, bv.w };
            #pragma unroll
            for (int i = 0; i < 4; ++i)
                #pragma unroll
                for (int j = 0; j < 4; ++j)
                    acc[i][j] += a_[i] * b_[j];
        }
        __syncthreads();
    }

    #pragma unroll
    for (int i = 0; i < 4; ++i) {
        const int m = m0 + ty * 4 + i;
        #pragma unroll
        for (int j = 0; j < 4; ++j) {
            const int nn = n0 + tx * 4 + j;
            float v = acc[i][j] + bias[nn];
            if (GELU_ACT) v = 0.5f * v * (1.f + erff(v * 0.70710678118f));
            if (RES) v += ldf(&res[(size_t)m * N + nn]);
            stf(&out[(size_t)m * N + nn], v);
        }
    }
}

// ---------------- overlapping-window attention ----------------
// one block per window (6272), 128 threads; threads 0..95 = (head, qi)
__global__ __launch_bounds__(128) void attn_kernel(
    const bf16* __restrict__ qkv, const float* __restrict__ rpb,
    bf16* __restrict__ out)
{
    __shared__ float ks[6 * 36 * 36];   // [h][kj][d] stride 36
    __shared__ float vs[6 * 36 * 36];
    const int w = blockIdx.x;
    const int b = w / (NHW * NHW), wi = w % (NHW * NHW);
    const int nhi = wi / NHW, nwi = wi % NHW;
    const int tid = threadIdx.x;
    const int r0 = nhi * 4 - 1, c0 = nwi * 4 - 1;

    for (int u = 0; u < 54; ++u) {      // 6*36*32 / 128
        int li = tid + u * 128;
        int h = li / 1152, rem = li % 1152, kj = rem >> 5, d = rem & 31;
        int rr = r0 + kj / 6, cc = c0 + kj % 6;
        float kvl = 0.f, vvl = 0.f;
        if (rr >= 0 && rr < CH && cc >= 0 && cc < CW) {
            size_t base = ((size_t)((b * CH + rr) * CW + cc)) * 576 + h * 32 + d;
            kvl = ldf(&qkv[base + 192]);
            vvl = ldf(&qkv[base + 384]);
        }
        ks[(h * 36 + kj) * 36 + d] = kvl;
        vs[(h * 36 + kj) * 36 + d] = vvl;
    }
    __syncthreads();

    if (tid < 96) {
        const int h = tid >> 4, qi = tid & 15;
        const int qr = nhi * 4 + (qi >> 2), qc = nwi * 4 + (qi & 3);
        const bf16* qp = qkv + ((size_t)((b * CH + qr) * CW + qc)) * 576 + h * 32;
        float qv[32];
        #pragma unroll
        for (int d = 0; d < 32; ++d) qv[d] = ldf(&qp[d]) * 0.17677669529f; // 1/sqrt(32)

        float sc[36];
        #pragma unroll
        for (int kj = 0; kj < 36; ++kj) {
            const float4* kr = (const float4*)(ks + (size_t)(h * 36 + kj) * 36);
            float a = 0.f;
            #pragma unroll
            for (int d4 = 0; d4 < 8; ++d4) {
                float4 k4 = kr[d4];
                a += qv[4 * d4 + 0] * k4.x + qv[4 * d4 + 1] * k4.y +
                     qv[4 * d4 + 2] * k4.z + qv[4 * d4 + 3] * k4.w;
            }
            const int rel0 = kj / 6 - (qi >> 2) + 3;
            const int rel1 = kj % 6 - (qi & 3) + 3;
            sc[kj] = a + rpb[(rel0 * 9 + rel1) * 6 + h];
        }
        float mx = -1e30f;
        #pragma unroll
        for (int kj = 0; kj < 36; ++kj) mx = fmaxf(mx, sc[kj]);
        float sum = 0.f;
        #pragma unroll
        for (int kj = 0; kj < 36; ++kj) { sc[kj] = expf(sc[kj] - mx); sum += sc[kj]; }
        const float inv = 1.f / sum;

        float o[32];
        #pragma unroll
        for (int d = 0; d < 32; ++d) o[d] = 0.f;
        #pragma unroll
        for (int kj = 0; kj < 36; ++kj) {
            const float4* vr = (const float4*)(vs + (size_t)(h * 36 + kj) * 36);
            const float p = sc[kj];
            #pragma unroll
            for (int d4 = 0; d4 < 8; ++d4) {
                float4 v4 = vr[d4];
                o[4 * d4 + 0] += p * v4.x; o[4 * d4 + 1] += p * v4.y;
                o[4 * d4 + 2] += p * v4.z; o[4 * d4 + 3] += p * v4.w;
            }
        }
        bf16* op = out + ((size_t)(b * TOKPB + qr * CW + qc)) * 192 + h * 32;
        #pragma unroll
        for (int d = 0; d < 32; ++d) stf(&op[d], o[d] * inv);
    }
}

// ---------------- final: out = relu(C2 + conv1x1(x)), in-place on d_out ----------------
__global__ __launch_bounds__(256) void final_kernel(
    const float* __restrict__ x, const float* __restrict__ w3t,
    const float* __restrict__ b3, float* __restrict__ io)
{
    __shared__ float xs[32][64];
    __shared__ float wsm[32][192];
    const int pix0 = blockIdx.x * 64;
    const int b    = blockIdx.y;
    const int tid = threadIdx.x, tx = tid & 15, ty = tid >> 4;
    float acc[12][4] = {};
    const size_t xbase = (size_t)b * (192 * TOKPB) + pix0;

    for (int k0 = 0; k0 < 192; k0 += 32) {
        #pragma unroll
        for (int u = 0; u < 8; ++u) {
            int li = tid + u * 256;
            int kk = li >> 6, p = li & 63;
            xs[kk][p] = x[xbase + (size_t)(k0 + kk) * TOKPB + p];
        }
        #pragma unroll
        for (int u = 0; u < 24; ++u) {
            int li = tid + u * 256;
            int kk = li / 192, c = li % 192;
            wsm[kk][c] = w3t[(k0 + kk) * 192 + c];
        }
        __syncthreads();
        #pragma unroll
        for (int kk = 0; kk < 32; ++kk) {
            float wv[12];
            #pragma unroll
            for (int i = 0; i < 12; ++i) wv[i] = wsm[kk][ty * 12 + i];
            float4 xq = *(const float4*)&xs[kk][tx * 4];
            float xv[4] = { xq.x, xq.y, xq.z, xq.w };
            #pragma unroll
            for (int i = 0; i < 12; ++i)
                #pragma unroll
                for (int j = 0; j < 4; ++j)
                    acc[i][j] += wv[i] * xv[j];
        }
        __syncthreads();
    }

    #pragma unroll
    for (int i = 0; i < 12; ++i) {
        const int co = ty * 12 + i;
        const size_t obase = (size_t)b * (192 * TOKPB) + (size_t)co * TOKPB + pix0 + tx * 4;
        float4 cv = *(const float4*)&io[obase];   // C2 (conv2+gn2 result)
        const float bb = b3[co];
        float4 o;
        o.x = fmaxf(acc[i][0] + bb + cv.x, 0.f);
        o.y = fmaxf(acc[i][1] + bb + cv.y, 0.f);
        o.z = fmaxf(acc[i][2] + bb + cv.z, 0.f);
        o.w = fmaxf(acc[i][3] + bb + cv.w, 0.f);
        *(float4*)&io[obase] = o;
    }
}

// ---------------- host launch ----------------
extern "C" void kernel_launch(void* const* d_in, const int* in_sizes, int n_in,
                              void* d_out, int out_size, void* d_ws, size_t ws_size,
                              hipStream_t stream)
{
    if (ws_size < WS_NEEDED) return;   // diagnostic guard: clean fail instead of device fault

    const float* x       = (const float*)d_in[0];
    const float* conv1_w = (const float*)d_in[1];
    const float* conv1_b = (const float*)d_in[2];
    const float* gn1_g   = (const float*)d_in[3];
    const float* gn1_b   = (const float*)d_in[4];
    const float* conv2_w = (const float*)d_in[5];
    const float* conv2_b = (const float*)d_in[6];
    const float* gn2_g   = (const float*)d_in[7];
    const float* gn2_b   = (const float*)d_in[8];
    const float* conv3_w = (const float*)d_in[9];
    const float* conv3_b = (const float*)d_in[10];
    const float* ln1_g   = (const float*)d_in[11];
    const float* ln1_b   = (const float*)d_in[12];
    const float* qkv_w   = (const float*)d_in[13];
    const float* qkv_b   = (const float*)d_in[14];
    const float* rpb     = (const float*)d_in[15];
    const float* proj_w  = (const float*)d_in[16];
    const float* proj_b  = (const float*)d_in[17];
    const float* ln2_g   = (const float*)d_in[18];
    const float* ln2_b   = (const float*)d_in[19];
    const float* fc1_w   = (const float*)d_in[20];
    const float* fc1_b   = (const float*)d_in[21];
    const float* fc2_w   = (const float*)d_in[22];
    const float* fc2_b   = (const float*)d_in[23];

    char* wsb = (char*)d_ws;
    bf16*  T0  = (bf16*)(wsb + B_T0);    // conv1+gn1+silu, token layout [A..E]
    bf16*  P2  = (bf16*)(wsb + B_P2);    // QKV [C..D], then HID [G..H]
    bf16*  P3  = (bf16*)(wsb + B_P3);    // XN [B..C], ATT [D..E], XM [F..G]
    bf16*  P4  = (bf16*)(wsb + B_P4);    // OMID [E..H]
    float* W1T = (float*)(wsb + B_W1T);
    float* W2T = (float*)(wsb + B_W2T);
    float* W3T = (float*)(wsb + B_W3T);
    float* OUT = (float*)d_out;          // OCAB [H..I] token layout, C2 [I..J] flat, final [J]

    // weight transposes
    transpose_w_kernel<<<(192 * 192 * 9 + 255) / 256, 256, 0, stream>>>(conv1_w, W1T);
    transpose_w_kernel<<<(192 * 192 * 9 + 255) / 256, 256, 0, stream>>>(conv2_w, W2T);
    transpose_w3_kernel<<<(192 * 192 + 255) / 256, 256, 0, stream>>>(conv3_w, W3T);

    // stage A: conv1 + gn1 + silu -> T0 (token layout, bf16)
    conv_gn_kernel<true, float, bf16><<<NPATCH, 192, 0, stream>>>(x, W1T, conv1_b, gn1_g, gn1_b, T0);
    // stage B: LN1 -> P3 (XN)
    ln_kernel<<<MTOK / 4, 256, 0, stream>>>(T0, ln1_g, ln1_b, P3);
    // stage C: qkv gemm -> P2 (QKV)
    gemm_kernel<bf16, bf16, false, false><<<dim3(MTOK / 64, 9), 256, 0, stream>>>(P3, qkv_w, qkv_b, nullptr, P2, 192, 576);
    // stage D: attention -> P3 (ATT)
    attn_kernel<<<NPATCH, 128, 0, stream>>>(P2, rpb, P3);
    // stage E: proj + shortcut(T0) -> P4 (OMID)
    gemm_kernel<bf16, bf16, true, false><<<dim3(MTOK / 64, 3), 256, 0, stream>>>(P3, proj_w, proj_b, T0, P4, 192, 192);
    // stage F: LN2 -> P3 (XM)
    ln_kernel<<<MTOK / 4, 256, 0, stream>>>(P4, ln2_g, ln2_b, P3);
    // stage G: fc1 + gelu -> P2 (HID)
    gemm_kernel<bf16, bf16, false, true><<<dim3(MTOK / 64, 6), 256, 0, stream>>>(P3, fc1_w, fc1_b, nullptr, P2, 192, 384);
    // stage H: fc2 + residual(OMID) -> d_out (OCAB, token layout, f32)
    gemm_kernel<bf16, float, true, false><<<dim3(MTOK / 64, 3), 256, 0, stream>>>(P2, fc2_w, fc2_b, P4, OUT, 384, 192);
    // stage I: conv2 + gn2, token->flat IN-PLACE on d_out (patch range identical, LDS-staged)
    conv_gn_kernel<false, float, float><<<NPATCH, 192, 0, stream>>>(OUT, W2T, conv2_b, gn2_g, gn2_b, OUT);
    // stage J: out = relu(C2 + conv1x1(x)), in-place on d_out
    final_kernel<<<dim3(TOKPB / 64, CB), 256, 0, stream>>>(x, W3T, conv3_b, OUT);
}

// Round 3
// 1680.714 us; speedup vs baseline: 1.9608x; 1.9608x over previous
//
#include <hip/hip_runtime.h>
#include <hip/hip_bf16.h>
#include <math.h>

typedef __hip_bfloat16 bf16;
typedef __attribute__((ext_vector_type(8))) short s8v;
typedef __attribute__((ext_vector_type(4))) short s4v;
typedef __attribute__((ext_vector_type(4))) float f32x4;

// ---------------- problem constants ----------------
constexpr int CB   = 2;            // batch
constexpr int CH   = 224, CW = 224;
constexpr int NHW  = 56;           // H/WS
constexpr int NPATCH = CB * NHW * NHW;   // 6272
constexpr int TOKPB  = CH * CW;          // 50176 tokens per batch
constexpr int MTOK   = CB * TOKPB;       // 100352 rows

// ---------------- ws layout (BYTE offsets) ----------------
constexpr size_t B_T0  = 0;                         // 19267584 bf16
constexpr size_t B_P2  = B_T0 + 38535168;           // 57802752 bf16 (QKV; later HID)
constexpr size_t B_P3  = B_P2 + 115605504;          // 19267584 bf16 (XN -> ATT -> XM)
constexpr size_t B_P4  = B_P3 + 38535168;           // 19267584 bf16 (OMID, then C2)
constexpr size_t B_WF1 = B_P4 + 38535168;           // 331776 bf16 frag-packed conv1 weights
constexpr size_t B_WF2 = B_WF1 + 1327104;           // 331776 bf16 frag-packed conv2 weights
constexpr size_t B_W3T = B_WF2 + 1327104;           // 36864 f32
constexpr size_t WS_NEEDED = B_W3T + 147456;        // 234,012,672 B

// ---------------- type helpers ----------------
__device__ __forceinline__ float ldf(const float* p) { return *p; }
__device__ __forceinline__ float ldf(const bf16* p)  { return __bfloat162float(*p); }
__device__ __forceinline__ void  stf(float* p, float v) { *p = v; }
__device__ __forceinline__ void  stf(bf16* p, float v)  { *p = __float2bfloat16(v); }
__device__ __forceinline__ unsigned short f2bf(float f) {
    unsigned u = __builtin_bit_cast(unsigned, f);
    unsigned r = (u + 0x7fffu + ((u >> 16) & 1u)) >> 16;
    return (unsigned short)r;
}
__device__ __forceinline__ float bf2f(short s) {
    unsigned u = ((unsigned)(unsigned short)s) << 16;
    return __builtin_bit_cast(float, u);
}

// ---------------- weight pre-pack (MFMA fragment order, bf16) ----------------
// wf[((tap*6+ks)*12+nt)*512 + l*8 + j] = w[co=nt*16+(l&15)][ci=ks*32+(l>>4)*8+j][tap]
__global__ void build_wf_kernel(const float* __restrict__ w, short* __restrict__ wf) {
    int o = blockIdx.x * 256 + threadIdx.x;
    if (o >= 331776) return;
    int within = o & 511, frag = o >> 9;
    int l = within >> 3, j = within & 7;
    int nt = frag % 12, t2 = frag / 12, ks = t2 % 6, tap = t2 / 6;
    int co = nt * 16 + (l & 15);
    int ci = ks * 32 + (l >> 4) * 8 + j;
    wf[o] = (short)f2bf(w[(co * 192 + ci) * 9 + tap]);
}
__global__ void transpose_w3_kernel(const float* __restrict__ w, float* __restrict__ wt) {
    int o = blockIdx.x * 256 + threadIdx.x;
    if (o >= 192 * 192) return;
    int ci = o / 192, co = o % 192;      // wt[ci*192+co]
    wt[o] = w[co * 192 + ci];
}

// ---------------- conv3x3 (4x4 patches) + groupnorm (+silu), MFMA ----------------
// 8 patches/block, 256 threads (4 waves). Wave w owns n-tiles 3w..3w+2 (co w*48..w*48+47),
// all 8 patches. Per tap: A = row-shifted X (zero row 16 per patch for invalid taps).
// FIRST=true : src = x f32 patch-flat (ci-major), dst = T0 bf16 token layout, SiLU.
// FIRST=false: src = f32 token layout (d_out/OCAB), dst = bf16 patch-flat (P4/C2).
template <bool FIRST>
__global__ __launch_bounds__(256) void conv_mfma_kernel(
    const float* __restrict__ src, const short* __restrict__ wf,
    const float* __restrict__ bias, const float* __restrict__ gng,
    const float* __restrict__ gnb, bf16* __restrict__ dst)
{
    __shared__ short xs[26112];          // 8 patches * 17 rows * 384B (row 16 = zeros), swizzled
    __shared__ float gsum[8][6], gsum2[8][6], gmu[8][6], grs[8][6];
    const int tid  = threadIdx.x;
    const int lane = tid & 63, wid = tid >> 6;
    const int n0   = blockIdx.x * 8;

    if (tid < 48) { gsum[tid / 6][tid % 6] = 0.f; gsum2[tid / 6][tid % 6] = 0.f; }
    for (int u = tid; u < 8 * 192; u += 256) {       // zero rows
        int q = u / 192;
        xs[q * 3264 + 3072 + (u % 192)] = 0;
    }

    const float4* sp = (const float4*)(src + (size_t)n0 * 3072);
    if (FIRST) {
        #pragma unroll
        for (int u = 0; u < 24; ++u) {
            int idx = u * 256 + tid;                 // float4 index, 6144 total
            float4 v = sp[idx];
            int q = idx / 768;
            int li = (idx % 768) * 4;                // li = ci*16 + p
            int ci = li >> 4, p0 = li & 15;
            float vv[4] = { v.x, v.y, v.z, v.w };
            #pragma unroll
            for (int k = 0; k < 4; ++k) {
                int row = p0 + k;
                int ba = q * 6528 + ((row * 384 + ci * 2) ^ ((row & 7) << 4));
                *(short*)((char*)xs + ba) = (short)f2bf(vv[k]);
            }
        }
    } else {
        #pragma unroll
        for (int u = 0; u < 24; ++u) {
            int idx = u * 256 + tid;
            float4 v = sp[idx];
            int r = idx / 48;                        // row 0..127 (token within block)
            int c0 = (idx % 48) * 4;
            int q = r >> 4, rl = r & 15;
            s4v pk = { (short)f2bf(v.x), (short)f2bf(v.y), (short)f2bf(v.z), (short)f2bf(v.w) };
            int ba = q * 6528 + ((rl * 384 + c0 * 2) ^ ((rl & 7) << 4));
            *(s4v*)((char*)xs + ba) = pk;
        }
    }
    __syncthreads();

    const int ntb = wid * 3;
    const int cl  = lane & 15;       // A-row (= output pos p) / B-col (= co within tile)
    const int kg  = lane >> 4;
    f32x4 acc[3][8];
    #pragma unroll
    for (int t = 0; t < 3; ++t) {
        float bv = bias[(ntb + t) * 16 + cl];
        #pragma unroll
        for (int q = 0; q < 8; ++q) acc[t][q] = (f32x4){ bv, bv, bv, bv };
    }

    const int pi = cl >> 2, pj = cl & 3;
    const s8v* wf8 = (const s8v*)wf;

    for (int tap = 0; tap < 9; ++tap) {
        const int di = tap / 3, dj = tap % 3;
        const int ii = pi + di - 1, jj = pj + dj - 1;
        const bool valid = (ii >= 0 && ii < 4 && jj >= 0 && jj < 4);
        const int nr  = valid ? (ii * 4 + jj) : 16;   // row 16 = zero row
        const int rb  = nr * 384;
        const int swz = (nr & 7) << 4;
        #pragma unroll
        for (int ks = 0; ks < 6; ++ks) {
            const s8v* bp = wf8 + (size_t)((tap * 6 + ks) * 12) * 64 + lane;
            s8v b0 = bp[(ntb + 0) * 64];
            s8v b1 = bp[(ntb + 1) * 64];
            s8v b2 = bp[(ntb + 2) * 64];
            const int inner = (rb + ks * 64 + kg * 16) ^ swz;
            #pragma unroll
            for (int q = 0; q < 8; ++q) {
                s8v a = *(const s8v*)((const char*)xs + q * 6528 + inner);
                acc[0][q] = __builtin_amdgcn_mfma_f32_16x16x32_bf16(a, b0, acc[0][q], 0, 0, 0);
                acc[1][q] = __builtin_amdgcn_mfma_f32_16x16x32_bf16(a, b1, acc[1][q], 0, 0, 0);
                acc[2][q] = __builtin_amdgcn_mfma_f32_16x16x32_bf16(a, b2, acc[2][q], 0, 0, 0);
            }
        }
    }

    // group stats: group g = co/32 = nt>>1 (uniform per fragment), 512 vals per (patch,group)
    #pragma unroll
    for (int t = 0; t < 3; ++t) {
        const int g = (ntb + t) >> 1;
        #pragma unroll
        for (int q = 0; q < 8; ++q) {
            f32x4 A = acc[t][q];
            float s  = A[0] + A[1] + A[2] + A[3];
            float s2 = A[0]*A[0] + A[1]*A[1] + A[2]*A[2] + A[3]*A[3];
            #pragma unroll
            for (int off = 32; off; off >>= 1) { s += __shfl_xor(s, off); s2 += __shfl_xor(s2, off); }
            if (lane == 0) { atomicAdd(&gsum[q][g], s); atomicAdd(&gsum2[q][g], s2); }
        }
    }
    __syncthreads();
    if (tid < 48) {
        int q = tid / 6, g = tid % 6;
        float mu  = gsum[q][g] * (1.f / 512.f);
        float var = gsum2[q][g] * (1.f / 512.f) - mu * mu;
        gmu[q][g] = mu; grs[q][g] = rsqrtf(var + 1e-5f);
    }
    __syncthreads();

    if (FIRST) {
        #pragma unroll
        for (int t = 0; t < 3; ++t) {
            const int co = (ntb + t) * 16 + cl, g = (ntb + t) >> 1;
            const float gg = gng[co], gb = gnb[co];
            #pragma unroll
            for (int q = 0; q < 8; ++q) {
                const float mu = gmu[q][g], rs = grs[q][g];
                bf16* op = dst + (((size_t)(n0 + q) * 16) + kg * 4) * 192 + co;
                #pragma unroll
                for (int r = 0; r < 4; ++r) {
                    float v = (acc[t][q][r] - mu) * rs * gg + gb;
                    v = v / (1.f + expf(-v));        // silu
                    op[(size_t)r * 192] = __float2bfloat16(v);
                }
            }
        }
    } else {
        // normalize -> LDS (patch-flat), then coalesced copy-out
        #pragma unroll
        for (int t = 0; t < 3; ++t) {
            const int co = (ntb + t) * 16 + cl, g = (ntb + t) >> 1;
            const float gg = gng[co], gb = gnb[co];
            #pragma unroll
            for (int q = 0; q < 8; ++q) {
                const float mu = gmu[q][g], rs = grs[q][g];
                #pragma unroll
                for (int r = 0; r < 4; ++r) {
                    float v = (acc[t][q][r] - mu) * rs * gg + gb;
                    xs[q * 3072 + co * 16 + kg * 4 + r] = (short)f2bf(v);
                }
            }
        }
        __syncthreads();
        s4v* dp = (s4v*)(dst + (size_t)n0 * 3072);
        const s4v* sps = (const s4v*)xs;
        #pragma unroll
        for (int u = 0; u < 24; ++u) {
            dp[u * 256 + tid] = sps[u * 256 + tid];
        }
    }
}

// ---------------- layernorm over last dim (192), bf16 -> bf16 ----------------
__global__ __launch_bounds__(256) void ln_kernel(
    const bf16* __restrict__ in, const float* __restrict__ g,
    const float* __restrict__ bb, bf16* __restrict__ out)
{
    const int row  = blockIdx.x * 4 + (threadIdx.x >> 6);
    const int lane = threadIdx.x & 63;
    const bf16* ip = in + (size_t)row * 192;
    float v0 = ldf(&ip[lane]), v1 = ldf(&ip[lane + 64]), v2 = ldf(&ip[lane + 128]);
    float s = v0 + v1 + v2, s2 = v0 * v0 + v1 * v1 + v2 * v2;
    #pragma unroll
    for (int off = 32; off; off >>= 1) { s += __shfl_xor(s, off); s2 += __shfl_xor(s2, off); }
    const float mu  = s * (1.f / 192.f);
    const float var = s2 * (1.f / 192.f) - mu * mu;
    const float rs  = rsqrtf(var + 1e-5f);
    bf16* op = out + (size_t)row * 192;
    stf(&op[lane],       (v0 - mu) * rs * g[lane]       + bb[lane]);
    stf(&op[lane + 64],  (v1 - mu) * rs * g[lane + 64]  + bb[lane + 64]);
    stf(&op[lane + 128], (v2 - mu) * rs * g[lane + 128] + bb[lane + 128]);
}

// ---------------- generic tiled GEMM: out = A(MxK) @ B(KxN) + bias (+res) (+gelu) ----------------
template <typename TA, typename TO, bool RES, bool GELU_ACT>
__global__ __launch_bounds__(256) void gemm_kernel(
    const TA* __restrict__ A, const float* __restrict__ Bw,
    const float* __restrict__ bias, const bf16* __restrict__ res,
    TO* __restrict__ out, int K, int N)
{
    __shared__ float As[32][68];
    __shared__ float Bs[32][64];
    const int m0 = blockIdx.x * 64;
    const int n0 = blockIdx.y * 64;
    const int tid = threadIdx.x;
    const int tx = tid & 15, ty = tid >> 4;
    float acc[4][4] = {};

    for (int k0 = 0; k0 < K; k0 += 32) {
        #pragma unroll
        for (int u = 0; u < 8; ++u) {
            int li = tid + u * 256;
            int r = li >> 5, kk = li & 31;
            As[kk][r] = ldf(&A[(size_t)(m0 + r) * K + k0 + kk]);
        }
        #pragma unroll
        for (int u = 0; u < 8; ++u) {
            int li = tid + u * 256;
            int kk = li >> 6, c = li & 63;
            Bs[kk][c] = Bw[(size_t)(k0 + kk) * N + n0 + c];
        }
        __syncthreads();
        #pragma unroll
        for (int kk = 0; kk < 32; ++kk) {
            float4 av = *(const float4*)&As[kk][ty * 4];
            float4 bv = *(const float4*)&Bs[kk][tx * 4];
            float a_[4] = { av.x, av.y, av.z, av.w };
            float b_[4] = { bv.x, bv.y, bv.z, bv.w };
            #pragma unroll
            for (int i = 0; i < 4; ++i)
                #pragma unroll
                for (int j = 0; j < 4; ++j)
                    acc[i][j] += a_[i] * b_[j];
        }
        __syncthreads();
    }

    #pragma unroll
    for (int i = 0; i < 4; ++i) {
        const int m = m0 + ty * 4 + i;
        #pragma unroll
        for (int j = 0; j < 4; ++j) {
            const int nn = n0 + tx * 4 + j;
            float v = acc[i][j] + bias[nn];
            if (GELU_ACT) v = 0.5f * v * (1.f + erff(v * 0.70710678118f));
            if (RES) v += ldf(&res[(size_t)m * N + nn]);
            stf(&out[(size_t)m * N + nn], v);
        }
    }
}

// ---------------- overlapping-window attention ----------------
__global__ __launch_bounds__(128) void attn_kernel(
    const bf16* __restrict__ qkv, const float* __restrict__ rpb,
    bf16* __restrict__ out)
{
    __shared__ float ks[6 * 36 * 36];   // [h][kj][d] stride 36
    __shared__ float vs[6 * 36 * 36];
    const int w = blockIdx.x;
    const int b = w / (NHW * NHW), wi = w % (NHW * NHW);
    const int nhi = wi / NHW, nwi = wi % NHW;
    const int tid = threadIdx.x;
    const int r0 = nhi * 4 - 1, c0 = nwi * 4 - 1;

    for (int u = 0; u < 54; ++u) {      // 6*36*32 / 128
        int li = tid + u * 128;
        int h = li / 1152, rem = li % 1152, kj = rem >> 5, d = rem & 31;
        int rr = r0 + kj / 6, cc = c0 + kj % 6;
        float kvl = 0.f, vvl = 0.f;
        if (rr >= 0 && rr < CH && cc >= 0 && cc < CW) {
            size_t base = ((size_t)((b * CH + rr) * CW + cc)) * 576 + h * 32 + d;
            kvl = ldf(&qkv[base + 192]);
            vvl = ldf(&qkv[base + 384]);
        }
        ks[(h * 36 + kj) * 36 + d] = kvl;
        vs[(h * 36 + kj) * 36 + d] = vvl;
    }
    __syncthreads();

    if (tid < 96) {
        const int h = tid >> 4, qi = tid & 15;
        const int qr = nhi * 4 + (qi >> 2), qc = nwi * 4 + (qi & 3);
        const bf16* qp = qkv + ((size_t)((b * CH + qr) * CW + qc)) * 576 + h * 32;
        float qv[32];
        #pragma unroll
        for (int d = 0; d < 32; ++d) qv[d] = ldf(&qp[d]) * 0.17677669529f;

        float sc[36];
        #pragma unroll
        for (int kj = 0; kj < 36; ++kj) {
            const float4* kr = (const float4*)(ks + (size_t)(h * 36 + kj) * 36);
            float a = 0.f;
            #pragma unroll
            for (int d4 = 0; d4 < 8; ++d4) {
                float4 k4 = kr[d4];
                a += qv[4 * d4 + 0] * k4.x + qv[4 * d4 + 1] * k4.y +
                     qv[4 * d4 + 2] * k4.z + qv[4 * d4 + 3] * k4.w;
            }
            const int rel0 = kj / 6 - (qi >> 2) + 3;
            const int rel1 = kj % 6 - (qi & 3) + 3;
            sc[kj] = a + rpb[(rel0 * 9 + rel1) * 6 + h];
        }
        float mx = -1e30f;
        #pragma unroll
        for (int kj = 0; kj < 36; ++kj) mx = fmaxf(mx, sc[kj]);
        float sum = 0.f;
        #pragma unroll
        for (int kj = 0; kj < 36; ++kj) { sc[kj] = expf(sc[kj] - mx); sum += sc[kj]; }
        const float inv = 1.f / sum;

        float o[32];
        #pragma unroll
        for (int d = 0; d < 32; ++d) o[d] = 0.f;
        #pragma unroll
        for (int kj = 0; kj < 36; ++kj) {
            const float4* vr = (const float4*)(vs + (size_t)(h * 36 + kj) * 36);
            const float p = sc[kj];
            #pragma unroll
            for (int d4 = 0; d4 < 8; ++d4) {
                float4 v4 = vr[d4];
                o[4 * d4 + 0] += p * v4.x; o[4 * d4 + 1] += p * v4.y;
                o[4 * d4 + 2] += p * v4.z; o[4 * d4 + 3] += p * v4.w;
            }
        }
        bf16* op = out + ((size_t)(b * TOKPB + qr * CW + qc)) * 192 + h * 32;
        #pragma unroll
        for (int d = 0; d < 32; ++d) stf(&op[d], o[d] * inv);
    }
}

// ---------------- final: out = relu(C2 + conv1x1(x)) ----------------
__global__ __launch_bounds__(256) void final_kernel(
    const float* __restrict__ x, const float* __restrict__ w3t,
    const float* __restrict__ b3, const bf16* __restrict__ c2,
    float* __restrict__ out)
{
    __shared__ float xs[32][64];
    __shared__ float wsm[32][192];
    const int pix0 = blockIdx.x * 64;
    const int b    = blockIdx.y;
    const int tid = threadIdx.x, tx = tid & 15, ty = tid >> 4;
    float acc[12][4] = {};
    const size_t xbase = (size_t)b * (192 * TOKPB) + pix0;

    for (int k0 = 0; k0 < 192; k0 += 32) {
        #pragma unroll
        for (int u = 0; u < 8; ++u) {
            int li = tid + u * 256;
            int kk = li >> 6, p = li & 63;
            xs[kk][p] = x[xbase + (size_t)(k0 + kk) * TOKPB + p];
        }
        #pragma unroll
        for (int u = 0; u < 24; ++u) {
            int li = tid + u * 256;
            int kk = li / 192, c = li % 192;
            wsm[kk][c] = w3t[(k0 + kk) * 192 + c];
        }
        __syncthreads();
        #pragma unroll
        for (int kk = 0; kk < 32; ++kk) {
            float wv[12];
            #pragma unroll
            for (int i = 0; i < 12; ++i) wv[i] = wsm[kk][ty * 12 + i];
            float4 xq = *(const float4*)&xs[kk][tx * 4];
            float xv[4] = { xq.x, xq.y, xq.z, xq.w };
            #pragma unroll
            for (int i = 0; i < 12; ++i)
                #pragma unroll
                for (int j = 0; j < 4; ++j)
                    acc[i][j] += wv[i] * xv[j];
        }
        __syncthreads();
    }

    #pragma unroll
    for (int i = 0; i < 12; ++i) {
        const int co = ty * 12 + i;
        const size_t obase = (size_t)b * (192 * TOKPB) + (size_t)co * TOKPB + pix0 + tx * 4;
        s4v cs = *(const s4v*)(c2 + obase);    // C2 bf16, patch-flat == ref flat order
        const float bb = b3[co];
        float4 o;
        o.x = fmaxf(acc[i][0] + bb + bf2f(cs[0]), 0.f);
        o.y = fmaxf(acc[i][1] + bb + bf2f(cs[1]), 0.f);
        o.z = fmaxf(acc[i][2] + bb + bf2f(cs[2]), 0.f);
        o.w = fmaxf(acc[i][3] + bb + bf2f(cs[3]), 0.f);
        *(float4*)&out[obase] = o;
    }
}

// ---------------- host launch ----------------
extern "C" void kernel_launch(void* const* d_in, const int* in_sizes, int n_in,
                              void* d_out, int out_size, void* d_ws, size_t ws_size,
                              hipStream_t stream)
{
    if (ws_size < WS_NEEDED) return;

    const float* x       = (const float*)d_in[0];
    const float* conv1_w = (const float*)d_in[1];
    const float* conv1_b = (const float*)d_in[2];
    const float* gn1_g   = (const float*)d_in[3];
    const float* gn1_b   = (const float*)d_in[4];
    const float* conv2_w = (const float*)d_in[5];
    const float* conv2_b = (const float*)d_in[6];
    const float* gn2_g   = (const float*)d_in[7];
    const float* gn2_b   = (const float*)d_in[8];
    const float* conv3_w = (const float*)d_in[9];
    const float* conv3_b = (const float*)d_in[10];
    const float* ln1_g   = (const float*)d_in[11];
    const float* ln1_b   = (const float*)d_in[12];
    const float* qkv_w   = (const float*)d_in[13];
    const float* qkv_b   = (const float*)d_in[14];
    const float* rpb     = (const float*)d_in[15];
    const float* proj_w  = (const float*)d_in[16];
    const float* proj_b  = (const float*)d_in[17];
    const float* ln2_g   = (const float*)d_in[18];
    const float* ln2_b   = (const float*)d_in[19];
    const float* fc1_w   = (const float*)d_in[20];
    const float* fc1_b   = (const float*)d_in[21];
    const float* fc2_w   = (const float*)d_in[22];
    const float* fc2_b   = (const float*)d_in[23];

    char* wsb = (char*)d_ws;
    bf16*  T0  = (bf16*)(wsb + B_T0);
    bf16*  P2  = (bf16*)(wsb + B_P2);
    bf16*  P3  = (bf16*)(wsb + B_P3);
    bf16*  P4  = (bf16*)(wsb + B_P4);
    short* WF1 = (short*)(wsb + B_WF1);
    short* WF2 = (short*)(wsb + B_WF2);
    float* W3T = (float*)(wsb + B_W3T);
    float* OUT = (float*)d_out;

    // weight prep
    build_wf_kernel<<<(331776 + 255) / 256, 256, 0, stream>>>(conv1_w, WF1);
    build_wf_kernel<<<(331776 + 255) / 256, 256, 0, stream>>>(conv2_w, WF2);
    transpose_w3_kernel<<<(192 * 192 + 255) / 256, 256, 0, stream>>>(conv3_w, W3T);

    // stage A: conv1 + gn1 + silu -> T0 (token layout, bf16)
    conv_mfma_kernel<true><<<NPATCH / 8, 256, 0, stream>>>(x, WF1, conv1_b, gn1_g, gn1_b, T0);
    // stage B: LN1 -> P3 (XN)
    ln_kernel<<<MTOK / 4, 256, 0, stream>>>(T0, ln1_g, ln1_b, P3);
    // stage C: qkv gemm -> P2 (QKV)
    gemm_kernel<bf16, bf16, false, false><<<dim3(MTOK / 64, 9), 256, 0, stream>>>(P3, qkv_w, qkv_b, nullptr, P2, 192, 576);
    // stage D: attention -> P3 (ATT)
    attn_kernel<<<NPATCH, 128, 0, stream>>>(P2, rpb, P3);
    // stage E: proj + shortcut(T0) -> P4 (OMID)
    gemm_kernel<bf16, bf16, true, false><<<dim3(MTOK / 64, 3), 256, 0, stream>>>(P3, proj_w, proj_b, T0, P4, 192, 192);
    // stage F: LN2 -> P3 (XM)
    ln_kernel<<<MTOK / 4, 256, 0, stream>>>(P4, ln2_g, ln2_b, P3);
    // stage G: fc1 + gelu -> P2 (HID)
    gemm_kernel<bf16, bf16, false, true><<<dim3(MTOK / 64, 6), 256, 0, stream>>>(P3, fc1_w, fc1_b, nullptr, P2, 192, 384);
    // stage H: fc2 + residual(OMID) -> d_out (OCAB, token layout, f32)
    gemm_kernel<bf16, float, true, false><<<dim3(MTOK / 64, 3), 256, 0, stream>>>(P2, fc2_w, fc2_b, P4, OUT, 384, 192);
    // stage I: conv2 + gn2 (reads d_out token layout) -> P4 (C2, bf16 patch-flat)
    conv_mfma_kernel<false><<<NPATCH / 8, 256, 0, stream>>>(OUT, WF2, conv2_b, gn2_g, gn2_b, P4);
    // stage J: out = relu(C2 + conv1x1(x)) -> d_out
    final_kernel<<<dim3(TOKPB / 64, CB), 256, 0, stream>>>(x, W3T, conv3_b, P4, OUT);
}

// Round 4
// 897.737 us; speedup vs baseline: 3.6709x; 1.8722x over previous
//
#include <hip/hip_runtime.h>
#include <hip/hip_bf16.h>
#include <math.h>

typedef __hip_bfloat16 bf16;
typedef __attribute__((ext_vector_type(8))) short s8v;
typedef __attribute__((ext_vector_type(4))) short s4v;
typedef __attribute__((ext_vector_type(4))) float f32x4;
typedef __attribute__((ext_vector_type(2))) _Float16 h2;

// ---------------- problem constants ----------------
constexpr int CB   = 2;            // batch
constexpr int CH   = 224, CW = 224;
constexpr int NHW  = 56;           // H/WS
constexpr int NPATCH = CB * NHW * NHW;   // 6272
constexpr int TOKPB  = CH * CW;          // 50176 tokens per batch
constexpr int MTOK   = CB * TOKPB;       // 100352 rows

// ---------------- ws layout (BYTE offsets) ----------------
constexpr size_t B_T0  = 0;                         // 19267584 bf16
constexpr size_t B_P2  = B_T0 + 38535168;           // 57802752 bf16 (QKV; later HID)
constexpr size_t B_P3  = B_P2 + 115605504;          // 19267584 bf16 (XN -> ATT -> XM)
constexpr size_t B_P4  = B_P3 + 38535168;           // 19267584 bf16 (OMID, then C2)
constexpr size_t B_WF1 = B_P4 + 38535168;           // 331776 bf16 frag-packed conv1 weights
constexpr size_t B_WF2 = B_WF1 + 1327104;           // 331776 bf16 frag-packed conv2 weights
constexpr size_t B_W3T = B_WF2 + 1327104;           // 36864 f32
constexpr size_t B_WQ  = B_W3T + 147456;            // 110592 bf16 (qkv_w frag-packed)
constexpr size_t B_WP  = B_WQ + 221184;             // 36864 bf16 (proj_w)
constexpr size_t B_WG1 = B_WP + 73728;              // 73728 bf16 (fc1_w)
constexpr size_t B_WG2 = B_WG1 + 147456;            // 73728 bf16 (fc2_w)
constexpr size_t WS_NEEDED = B_WG2 + 147456;        // 234,602,496 B

// ---------------- type helpers ----------------
__device__ __forceinline__ float ldf(const float* p) { return *p; }
__device__ __forceinline__ float ldf(const bf16* p)  { return __bfloat162float(*p); }
__device__ __forceinline__ void  stf(float* p, float v) { *p = v; }
__device__ __forceinline__ void  stf(bf16* p, float v)  { *p = __float2bfloat16(v); }
__device__ __forceinline__ unsigned short f2bf(float f) {
    unsigned u = __builtin_bit_cast(unsigned, f);
    unsigned r = (u + 0x7fffu + ((u >> 16) & 1u)) >> 16;
    return (unsigned short)r;
}
__device__ __forceinline__ float bf2f(short s) {
    unsigned u = ((unsigned)(unsigned short)s) << 16;
    return __builtin_bit_cast(float, u);
}

// ---------------- conv weight pre-pack (MFMA fragment order, bf16) ----------------
__global__ void build_wf_kernel(const float* __restrict__ w, short* __restrict__ wf) {
    int o = blockIdx.x * 256 + threadIdx.x;
    if (o >= 331776) return;
    int within = o & 511, frag = o >> 9;
    int l = within >> 3, j = within & 7;
    int nt = frag % 12, t2 = frag / 12, ks = t2 % 6, tap = t2 / 6;
    int co = nt * 16 + (l & 15);
    int ci = ks * 32 + (l >> 4) * 8 + j;
    wf[o] = (short)f2bf(w[(co * 192 + ci) * 9 + tap]);
}
// generic GEMM weight pre-pack: w is K x N row-major f32 -> frag order bf16
// frag f = kt*(N/16)+nt ; elem = w[kt*32+(l>>4)*8+j][nt*16+(l&15)]
__global__ void build_wgemm_kernel(const float* __restrict__ w, short* __restrict__ wf,
                                   int K, int N) {
    int o = blockIdx.x * 256 + threadIdx.x;
    if (o >= K * N) return;
    int j = o & 7, l = (o >> 3) & 63, f = o >> 9;
    int ntiles = N >> 4;
    int kt = f / ntiles, nt = f % ntiles;
    int k = kt * 32 + (l >> 4) * 8 + j;
    int col = nt * 16 + (l & 15);
    wf[o] = (short)f2bf(w[(size_t)k * N + col]);
}
__global__ void transpose_w3_kernel(const float* __restrict__ w, float* __restrict__ wt) {
    int o = blockIdx.x * 256 + threadIdx.x;
    if (o >= 192 * 192) return;
    int ci = o / 192, co = o % 192;      // wt[ci*192+co]
    wt[o] = w[co * 192 + ci];
}

// ---------------- conv3x3 (4x4 patches) + groupnorm (+silu), MFMA ----------------
template <bool FIRST>
__global__ __launch_bounds__(256) void conv_mfma_kernel(
    const float* __restrict__ src, const short* __restrict__ wf,
    const float* __restrict__ bias, const float* __restrict__ gng,
    const float* __restrict__ gnb, bf16* __restrict__ dst)
{
    __shared__ short xs[26112];          // 8 patches * 17 rows * 384B (row 16 = zeros), swizzled
    __shared__ float gsum[8][6], gsum2[8][6], gmu[8][6], grs[8][6];
    const int tid  = threadIdx.x;
    const int lane = tid & 63, wid = tid >> 6;
    const int n0   = blockIdx.x * 8;

    if (tid < 48) { gsum[tid / 6][tid % 6] = 0.f; gsum2[tid / 6][tid % 6] = 0.f; }
    for (int u = tid; u < 8 * 192; u += 256) {       // zero rows
        int q = u / 192;
        xs[q * 3264 + 3072 + (u % 192)] = 0;
    }

    const float4* sp = (const float4*)(src + (size_t)n0 * 3072);
    if (FIRST) {
        #pragma unroll
        for (int u = 0; u < 24; ++u) {
            int idx = u * 256 + tid;                 // float4 index, 6144 total
            float4 v = sp[idx];
            int q = idx / 768;
            int li = (idx % 768) * 4;                // li = ci*16 + p
            int ci = li >> 4, p0 = li & 15;
            float vv[4] = { v.x, v.y, v.z, v.w };
            #pragma unroll
            for (int k = 0; k < 4; ++k) {
                int row = p0 + k;
                int ba = q * 6528 + ((row * 384 + ci * 2) ^ ((row & 7) << 4));
                *(short*)((char*)xs + ba) = (short)f2bf(vv[k]);
            }
        }
    } else {
        #pragma unroll
        for (int u = 0; u < 24; ++u) {
            int idx = u * 256 + tid;
            float4 v = sp[idx];
            int r = idx / 48;                        // row 0..127 (token within block)
            int c0 = (idx % 48) * 4;
            int q = r >> 4, rl = r & 15;
            s4v pk = { (short)f2bf(v.x), (short)f2bf(v.y), (short)f2bf(v.z), (short)f2bf(v.w) };
            int ba = q * 6528 + ((rl * 384 + c0 * 2) ^ ((rl & 7) << 4));
            *(s4v*)((char*)xs + ba) = pk;
        }
    }
    __syncthreads();

    const int ntb = wid * 3;
    const int cl  = lane & 15;       // A-row (= output pos p) / B-col (= co within tile)
    const int kg  = lane >> 4;
    f32x4 acc[3][8];
    #pragma unroll
    for (int t = 0; t < 3; ++t) {
        float bv = bias[(ntb + t) * 16 + cl];
        #pragma unroll
        for (int q = 0; q < 8; ++q) acc[t][q] = (f32x4){ bv, bv, bv, bv };
    }

    const int pi = cl >> 2, pj = cl & 3;
    const s8v* wf8 = (const s8v*)wf;

    for (int tap = 0; tap < 9; ++tap) {
        const int di = tap / 3, dj = tap % 3;
        const int ii = pi + di - 1, jj = pj + dj - 1;
        const bool valid = (ii >= 0 && ii < 4 && jj >= 0 && jj < 4);
        const int nr  = valid ? (ii * 4 + jj) : 16;   // row 16 = zero row
        const int rb  = nr * 384;
        const int swz = (nr & 7) << 4;
        #pragma unroll
        for (int ks = 0; ks < 6; ++ks) {
            const s8v* bp = wf8 + (size_t)((tap * 6 + ks) * 12) * 64 + lane;
            s8v b0 = bp[(ntb + 0) * 64];
            s8v b1 = bp[(ntb + 1) * 64];
            s8v b2 = bp[(ntb + 2) * 64];
            const int inner = (rb + ks * 64 + kg * 16) ^ swz;
            #pragma unroll
            for (int q = 0; q < 8; ++q) {
                s8v a = *(const s8v*)((const char*)xs + q * 6528 + inner);
                acc[0][q] = __builtin_amdgcn_mfma_f32_16x16x32_bf16(a, b0, acc[0][q], 0, 0, 0);
                acc[1][q] = __builtin_amdgcn_mfma_f32_16x16x32_bf16(a, b1, acc[1][q], 0, 0, 0);
                acc[2][q] = __builtin_amdgcn_mfma_f32_16x16x32_bf16(a, b2, acc[2][q], 0, 0, 0);
            }
        }
    }

    #pragma unroll
    for (int t = 0; t < 3; ++t) {
        const int g = (ntb + t) >> 1;
        #pragma unroll
        for (int q = 0; q < 8; ++q) {
            f32x4 A = acc[t][q];
            float s  = A[0] + A[1] + A[2] + A[3];
            float s2 = A[0]*A[0] + A[1]*A[1] + A[2]*A[2] + A[3]*A[3];
            #pragma unroll
            for (int off = 32; off; off >>= 1) { s += __shfl_xor(s, off); s2 += __shfl_xor(s2, off); }
            if (lane == 0) { atomicAdd(&gsum[q][g], s); atomicAdd(&gsum2[q][g], s2); }
        }
    }
    __syncthreads();
    if (tid < 48) {
        int q = tid / 6, g = tid % 6;
        float mu  = gsum[q][g] * (1.f / 512.f);
        float var = gsum2[q][g] * (1.f / 512.f) - mu * mu;
        gmu[q][g] = mu; grs[q][g] = rsqrtf(var + 1e-5f);
    }
    __syncthreads();

    if (FIRST) {
        #pragma unroll
        for (int t = 0; t < 3; ++t) {
            const int co = (ntb + t) * 16 + cl, g = (ntb + t) >> 1;
            const float gg = gng[co], gb = gnb[co];
            #pragma unroll
            for (int q = 0; q < 8; ++q) {
                const float mu = gmu[q][g], rs = grs[q][g];
                bf16* op = dst + (((size_t)(n0 + q) * 16) + kg * 4) * 192 + co;
                #pragma unroll
                for (int r = 0; r < 4; ++r) {
                    float v = (acc[t][q][r] - mu) * rs * gg + gb;
                    v = v / (1.f + expf(-v));        // silu
                    op[(size_t)r * 192] = __float2bfloat16(v);
                }
            }
        }
    } else {
        #pragma unroll
        for (int t = 0; t < 3; ++t) {
            const int co = (ntb + t) * 16 + cl, g = (ntb + t) >> 1;
            const float gg = gng[co], gb = gnb[co];
            #pragma unroll
            for (int q = 0; q < 8; ++q) {
                const float mu = gmu[q][g], rs = grs[q][g];
                #pragma unroll
                for (int r = 0; r < 4; ++r) {
                    float v = (acc[t][q][r] - mu) * rs * gg + gb;
                    xs[q * 3072 + co * 16 + kg * 4 + r] = (short)f2bf(v);
                }
            }
        }
        __syncthreads();
        s4v* dp = (s4v*)(dst + (size_t)n0 * 3072);
        const s4v* sps = (const s4v*)xs;
        #pragma unroll
        for (int u = 0; u < 24; ++u) {
            dp[u * 256 + tid] = sps[u * 256 + tid];
        }
    }
}

// ---------------- layernorm over last dim (192), bf16 -> bf16 ----------------
__global__ __launch_bounds__(256) void ln_kernel(
    const bf16* __restrict__ in, const float* __restrict__ g,
    const float* __restrict__ bb, bf16* __restrict__ out)
{
    const int row  = blockIdx.x * 4 + (threadIdx.x >> 6);
    const int lane = threadIdx.x & 63;
    const bf16* ip = in + (size_t)row * 192;
    float v0 = ldf(&ip[lane]), v1 = ldf(&ip[lane + 64]), v2 = ldf(&ip[lane + 128]);
    float s = v0 + v1 + v2, s2 = v0 * v0 + v1 * v1 + v2 * v2;
    #pragma unroll
    for (int off = 32; off; off >>= 1) { s += __shfl_xor(s, off); s2 += __shfl_xor(s2, off); }
    const float mu  = s * (1.f / 192.f);
    const float var = s2 * (1.f / 192.f) - mu * mu;
    const float rs  = rsqrtf(var + 1e-5f);
    bf16* op = out + (size_t)row * 192;
    stf(&op[lane],       (v0 - mu) * rs * g[lane]       + bb[lane]);
    stf(&op[lane + 64],  (v1 - mu) * rs * g[lane + 64]  + bb[lane + 64]);
    stf(&op[lane + 128], (v2 - mu) * rs * g[lane + 128] + bb[lane + 128]);
}

// ---------------- MFMA GEMM, zero-LDS: out = A(MxK)bf16 @ Wfrag + bias (+res)(+gelu) ----
// 256 thr = 4 waves; block tile 128x64. wave w: rows w*32..w*32+31 (2 frags), 4 col frags.
template <typename TO, bool RES, bool GELU_ACT>
__global__ __launch_bounds__(256) void gemm_mfma_kernel(
    const bf16* __restrict__ A, const short* __restrict__ wfb,
    const float* __restrict__ bias, const bf16* __restrict__ res,
    TO* __restrict__ out, int K, int N)
{
    const int tid = threadIdx.x, lane = tid & 63, wid = tid >> 6;
    const int m0 = blockIdx.x * 128, n0 = blockIdx.y * 64;
    const int cl = lane & 15, kg = lane >> 4;
    const int ntiles = N >> 4, nt0 = n0 >> 4;

    f32x4 acc[2][4];
    #pragma unroll
    for (int nf = 0; nf < 4; ++nf) {
        float bv = bias[n0 + nf * 16 + cl];
        acc[0][nf] = (f32x4){ bv, bv, bv, bv };
        acc[1][nf] = (f32x4){ bv, bv, bv, bv };
    }

    const s8v* wf8 = (const s8v*)wfb;
    const int nkt = K >> 5;
    for (int kt = 0; kt < nkt; ++kt) {
        s8v a0 = *(const s8v*)(A + (size_t)(m0 + wid * 32 +      cl) * K + kt * 32 + kg * 8);
        s8v a1 = *(const s8v*)(A + (size_t)(m0 + wid * 32 + 16 + cl) * K + kt * 32 + kg * 8);
        #pragma unroll
        for (int nf = 0; nf < 4; ++nf) {
            s8v b = wf8[(size_t)(kt * ntiles + nt0 + nf) * 64 + lane];
            acc[0][nf] = __builtin_amdgcn_mfma_f32_16x16x32_bf16(a0, b, acc[0][nf], 0, 0, 0);
            acc[1][nf] = __builtin_amdgcn_mfma_f32_16x16x32_bf16(a1, b, acc[1][nf], 0, 0, 0);
        }
    }

    #pragma unroll
    for (int rf = 0; rf < 2; ++rf) {
        #pragma unroll
        for (int nf = 0; nf < 4; ++nf) {
            const int col = n0 + nf * 16 + cl;
            #pragma unroll
            for (int r = 0; r < 4; ++r) {
                const int row = m0 + wid * 32 + rf * 16 + kg * 4 + r;
                float v = acc[rf][nf][r];
                if (GELU_ACT) v = 0.5f * v * (1.f + erff(v * 0.70710678118f));
                if (RES) v += ldf(&res[(size_t)row * N + col]);
                stf(&out[(size_t)row * N + col], v);
            }
        }
    }
}

// ---------------- overlapping-window attention (f16 LDS, fdot2) ----------------
// one block per window (6272), 128 threads; threads 0..95 = (head, qi)
constexpr int HSTR = 1160;   // per-head LDS stride in shorts (36*32 + 8 pad)
__global__ __launch_bounds__(128) void attn_kernel(
    const bf16* __restrict__ qkv, const float* __restrict__ rpb,
    bf16* __restrict__ out)
{
    __shared__ short kh[6 * HSTR];
    __shared__ short vh[6 * HSTR];
    const int w = blockIdx.x;
    const int b = w / (NHW * NHW), wi = w % (NHW * NHW);
    const int nhi = wi / NHW, nwi = wi % NHW;
    const int tid = threadIdx.x;
    const int r0 = nhi * 4 - 1, c0 = nwi * 4 - 1;

    // stage K/V: bf16 global -> f16 LDS. 1728 s4v units each.
    #pragma unroll
    for (int it = 0; it < 14; ++it) {
        int v = tid + it * 128;
        if (v < 1728) {
            int h = v / 288, rem = v % 288, kj = rem >> 3, d0 = (rem & 7) * 4;
            int rr = r0 + kj / 6, cc = c0 + kj % 6;
            s4v kvk = { 0, 0, 0, 0 }, kvv = { 0, 0, 0, 0 };
            if (rr >= 0 && rr < CH && cc >= 0 && cc < CW) {
                size_t base = ((size_t)((b * CH + rr) * CW + cc)) * 576 + h * 32 + d0;
                kvk = *(const s4v*)(qkv + base + 192);
                kvv = *(const s4v*)(qkv + base + 384);
            }
            s4v ko, vo;
            #pragma unroll
            for (int e = 0; e < 4; ++e) {
                ko[e] = __builtin_bit_cast(short, (_Float16)bf2f(kvk[e]));
                vo[e] = __builtin_bit_cast(short, (_Float16)bf2f(kvv[e]));
            }
            int off = h * HSTR + kj * 32 + d0;
            *(s4v*)(kh + off) = ko;
            *(s4v*)(vh + off) = vo;
        }
    }
    __syncthreads();

    if (tid < 96) {
        const int h = tid >> 4, qi = tid & 15;
        const int qr = nhi * 4 + (qi >> 2), qc = nwi * 4 + (qi & 3);
        const bf16* qp = qkv + ((size_t)((b * CH + qr) * CW + qc)) * 576 + h * 32;
        h2 qh[16];
        #pragma unroll
        for (int u = 0; u < 4; ++u) {
            s8v qv = *(const s8v*)(qp + u * 8);
            #pragma unroll
            for (int e = 0; e < 4; ++e) {
                h2 p;
                p[0] = (_Float16)bf2f(qv[2 * e]);
                p[1] = (_Float16)bf2f(qv[2 * e + 1]);
                qh[u * 4 + e] = p;
            }
        }

        float sc[36];
        const char* khb = (const char*)(kh + h * HSTR);
        #pragma unroll
        for (int kj = 0; kj < 36; ++kj) {
            const uint4* kp = (const uint4*)(khb + kj * 64);
            uint4 k0 = kp[0], k1 = kp[1], k2 = kp[2], k3 = kp[3];
            unsigned kwv[16] = { k0.x, k0.y, k0.z, k0.w, k1.x, k1.y, k1.z, k1.w,
                                 k2.x, k2.y, k2.z, k2.w, k3.x, k3.y, k3.z, k3.w };
            float a = 0.f;
            #pragma unroll
            for (int e = 0; e < 16; ++e)
                a = __builtin_amdgcn_fdot2(__builtin_bit_cast(h2, kwv[e]), qh[e], a, false);
            const int rel0 = kj / 6 - (qi >> 2) + 3;
            const int rel1 = kj % 6 - (qi & 3) + 3;
            sc[kj] = a * 0.17677669529f + rpb[(rel0 * 9 + rel1) * 6 + h];
        }
        float mx = -1e30f;
        #pragma unroll
        for (int kj = 0; kj < 36; ++kj) mx = fmaxf(mx, sc[kj]);
        float sum = 0.f;
        #pragma unroll
        for (int kj = 0; kj < 36; ++kj) { sc[kj] = expf(sc[kj] - mx); sum += sc[kj]; }
        const float inv = 1.f / sum;

        float o[32];
        #pragma unroll
        for (int d = 0; d < 32; ++d) o[d] = 0.f;
        const char* vhb = (const char*)(vh + h * HSTR);
        #pragma unroll
        for (int kj = 0; kj < 36; ++kj) {
            const uint4* vp = (const uint4*)(vhb + kj * 64);
            uint4 v0 = vp[0], v1 = vp[1], v2 = vp[2], v3 = vp[3];
            unsigned vwv[16] = { v0.x, v0.y, v0.z, v0.w, v1.x, v1.y, v1.z, v1.w,
                                 v2.x, v2.y, v2.z, v2.w, v3.x, v3.y, v3.z, v3.w };
            const float p = sc[kj];
            #pragma unroll
            for (int e = 0; e < 16; ++e) {
                h2 hv = __builtin_bit_cast(h2, vwv[e]);
                o[2 * e]     += p * (float)hv[0];
                o[2 * e + 1] += p * (float)hv[1];
            }
        }
        bf16* op = out + ((size_t)(b * TOKPB + qr * CW + qc)) * 192 + h * 32;
        #pragma unroll
        for (int u = 0; u < 8; ++u) {
            s4v pk;
            #pragma unroll
            for (int e = 0; e < 4; ++e) pk[e] = (short)f2bf(o[u * 4 + e] * inv);
            *(s4v*)((bf16*)op + u * 4) = pk;
        }
    }
}

// ---------------- final: out = relu(C2 + conv1x1(x)) ----------------
__global__ __launch_bounds__(256) void final_kernel(
    const float* __restrict__ x, const float* __restrict__ w3t,
    const float* __restrict__ b3, const bf16* __restrict__ c2,
    float* __restrict__ out)
{
    __shared__ float xs[32][64];
    __shared__ float wsm[32][192];
    const int pix0 = blockIdx.x * 64;
    const int b    = blockIdx.y;
    const int tid = threadIdx.x, tx = tid & 15, ty = tid >> 4;
    float acc[12][4] = {};
    const size_t xbase = (size_t)b * (192 * TOKPB) + pix0;

    for (int k0 = 0; k0 < 192; k0 += 32) {
        #pragma unroll
        for (int u = 0; u < 8; ++u) {
            int li = tid + u * 256;
            int kk = li >> 6, p = li & 63;
            xs[kk][p] = x[xbase + (size_t)(k0 + kk) * TOKPB + p];
        }
        #pragma unroll
        for (int u = 0; u < 24; ++u) {
            int li = tid + u * 256;
            int kk = li / 192, c = li % 192;
            wsm[kk][c] = w3t[(k0 + kk) * 192 + c];
        }
        __syncthreads();
        #pragma unroll
        for (int kk = 0; kk < 32; ++kk) {
            float wv[12];
            #pragma unroll
            for (int i = 0; i < 12; ++i) wv[i] = wsm[kk][ty * 12 + i];
            float4 xq = *(const float4*)&xs[kk][tx * 4];
            float xv[4] = { xq.x, xq.y, xq.z, xq.w };
            #pragma unroll
            for (int i = 0; i < 12; ++i)
                #pragma unroll
                for (int j = 0; j < 4; ++j)
                    acc[i][j] += wv[i] * xv[j];
        }
        __syncthreads();
    }

    #pragma unroll
    for (int i = 0; i < 12; ++i) {
        const int co = ty * 12 + i;
        const size_t obase = (size_t)b * (192 * TOKPB) + (size_t)co * TOKPB + pix0 + tx * 4;
        s4v cs = *(const s4v*)(c2 + obase);
        const float bb = b3[co];
        float4 o;
        o.x = fmaxf(acc[i][0] + bb + bf2f(cs[0]), 0.f);
        o.y = fmaxf(acc[i][1] + bb + bf2f(cs[1]), 0.f);
        o.z = fmaxf(acc[i][2] + bb + bf2f(cs[2]), 0.f);
        o.w = fmaxf(acc[i][3] + bb + bf2f(cs[3]), 0.f);
        *(float4*)&out[obase] = o;
    }
}

// ---------------- host launch ----------------
extern "C" void kernel_launch(void* const* d_in, const int* in_sizes, int n_in,
                              void* d_out, int out_size, void* d_ws, size_t ws_size,
                              hipStream_t stream)
{
    if (ws_size < WS_NEEDED) return;

    const float* x       = (const float*)d_in[0];
    const float* conv1_w = (const float*)d_in[1];
    const float* conv1_b = (const float*)d_in[2];
    const float* gn1_g   = (const float*)d_in[3];
    const float* gn1_b   = (const float*)d_in[4];
    const float* conv2_w = (const float*)d_in[5];
    const float* conv2_b = (const float*)d_in[6];
    const float* gn2_g   = (const float*)d_in[7];
    const float* gn2_b   = (const float*)d_in[8];
    const float* conv3_w = (const float*)d_in[9];
    const float* conv3_b = (const float*)d_in[10];
    const float* ln1_g   = (const float*)d_in[11];
    const float* ln1_b   = (const float*)d_in[12];
    const float* qkv_w   = (const float*)d_in[13];
    const float* qkv_b   = (const float*)d_in[14];
    const float* rpb     = (const float*)d_in[15];
    const float* proj_w  = (const float*)d_in[16];
    const float* proj_b  = (const float*)d_in[17];
    const float* ln2_g   = (const float*)d_in[18];
    const float* ln2_b   = (const float*)d_in[19];
    const float* fc1_w   = (const float*)d_in[20];
    const float* fc1_b   = (const float*)d_in[21];
    const float* fc2_w   = (const float*)d_in[22];
    const float* fc2_b   = (const float*)d_in[23];

    char* wsb = (char*)d_ws;
    bf16*  T0  = (bf16*)(wsb + B_T0);
    bf16*  P2  = (bf16*)(wsb + B_P2);
    bf16*  P3  = (bf16*)(wsb + B_P3);
    bf16*  P4  = (bf16*)(wsb + B_P4);
    short* WF1 = (short*)(wsb + B_WF1);
    short* WF2 = (short*)(wsb + B_WF2);
    float* W3T = (float*)(wsb + B_W3T);
    short* WQ  = (short*)(wsb + B_WQ);
    short* WP  = (short*)(wsb + B_WP);
    short* WG1 = (short*)(wsb + B_WG1);
    short* WG2 = (short*)(wsb + B_WG2);
    float* OUT = (float*)d_out;

    // weight prep
    build_wf_kernel<<<(331776 + 255) / 256, 256, 0, stream>>>(conv1_w, WF1);
    build_wf_kernel<<<(331776 + 255) / 256, 256, 0, stream>>>(conv2_w, WF2);
    transpose_w3_kernel<<<(192 * 192 + 255) / 256, 256, 0, stream>>>(conv3_w, W3T);
    build_wgemm_kernel<<<(110592 + 255) / 256, 256, 0, stream>>>(qkv_w, WQ, 192, 576);
    build_wgemm_kernel<<<(36864 + 255) / 256, 256, 0, stream>>>(proj_w, WP, 192, 192);
    build_wgemm_kernel<<<(73728 + 255) / 256, 256, 0, stream>>>(fc1_w, WG1, 192, 384);
    build_wgemm_kernel<<<(73728 + 255) / 256, 256, 0, stream>>>(fc2_w, WG2, 384, 192);

    // stage A: conv1 + gn1 + silu -> T0 (token layout, bf16)
    conv_mfma_kernel<true><<<NPATCH / 8, 256, 0, stream>>>(x, WF1, conv1_b, gn1_g, gn1_b, T0);
    // stage B: LN1 -> P3 (XN)
    ln_kernel<<<MTOK / 4, 256, 0, stream>>>(T0, ln1_g, ln1_b, P3);
    // stage C: qkv gemm -> P2 (QKV)
    gemm_mfma_kernel<bf16, false, false><<<dim3(MTOK / 128, 9), 256, 0, stream>>>(P3, WQ, qkv_b, nullptr, P2, 192, 576);
    // stage D: attention -> P3 (ATT)
    attn_kernel<<<NPATCH, 128, 0, stream>>>(P2, rpb, P3);
    // stage E: proj + shortcut(T0) -> P4 (OMID)
    gemm_mfma_kernel<bf16, true, false><<<dim3(MTOK / 128, 3), 256, 0, stream>>>(P3, WP, proj_b, T0, P4, 192, 192);
    // stage F: LN2 -> P3 (XM)
    ln_kernel<<<MTOK / 4, 256, 0, stream>>>(P4, ln2_g, ln2_b, P3);
    // stage G: fc1 + gelu -> P2 (HID)
    gemm_mfma_kernel<bf16, false, true><<<dim3(MTOK / 128, 6), 256, 0, stream>>>(P3, WG1, fc1_b, nullptr, P2, 192, 384);
    // stage H: fc2 + residual(OMID) -> d_out (OCAB, token layout, f32)
    gemm_mfma_kernel<float, true, false><<<dim3(MTOK / 128, 3), 256, 0, stream>>>(P2, WG2, fc2_b, P4, OUT, 384, 192);
    // stage I: conv2 + gn2 (reads d_out token layout) -> P4 (C2, bf16 patch-flat)
    conv_mfma_kernel<false><<<NPATCH / 8, 256, 0, stream>>>(OUT, WF2, conv2_b, gn2_g, gn2_b, P4);
    // stage J: out = relu(C2 + conv1x1(x)) -> d_out
    final_kernel<<<dim3(TOKPB / 64, CB), 256, 0, stream>>>(x, W3T, conv3_b, P4, OUT);
}

// Round 5
// 623.506 us; speedup vs baseline: 5.2854x; 1.4398x over previous
//
#include <hip/hip_runtime.h>
#include <hip/hip_bf16.h>
#include <math.h>

typedef __hip_bfloat16 bf16;
typedef __attribute__((ext_vector_type(8))) short s8v;
typedef __attribute__((ext_vector_type(4))) short s4v;
typedef __attribute__((ext_vector_type(4))) float f32x4;
typedef __attribute__((ext_vector_type(2))) _Float16 h2;

// ---------------- problem constants ----------------
constexpr int CB   = 2;            // batch
constexpr int CH   = 224, CW = 224;
constexpr int NHW  = 56;           // H/WS
constexpr int NPATCH = CB * NHW * NHW;   // 6272
constexpr int TOKPB  = CH * CW;          // 50176 tokens per batch
constexpr int MTOK   = CB * TOKPB;       // 100352 rows

// ---------------- ws layout (BYTE offsets) ----------------
constexpr size_t B_T0  = 0;                         // 19267584 bf16
constexpr size_t B_P2  = B_T0 + 38535168;           // 57802752 bf16 (QKV; later HID)
constexpr size_t B_P3  = B_P2 + 115605504;          // 19267584 bf16 (XN -> ATT -> XM)
constexpr size_t B_P4  = B_P3 + 38535168;           // 19267584 bf16 (OMID, then C2)
constexpr size_t B_WF1 = B_P4 + 38535168;           // 331776 bf16 frag-packed conv1 weights
constexpr size_t B_WF2 = B_WF1 + 1327104;           // 331776 bf16 frag-packed conv2 weights
constexpr size_t B_W3F = B_WF2 + 1327104;           // 36864 bf16 frag-packed conv3 (1x1)
constexpr size_t B_WQ  = B_W3F + 147456;            // 110592 bf16 (qkv_w frag-packed)
constexpr size_t B_WP  = B_WQ + 221184;             // 36864 bf16 (proj_w)
constexpr size_t B_WG1 = B_WP + 73728;              // 73728 bf16 (fc1_w)
constexpr size_t B_WG2 = B_WG1 + 147456;            // 73728 bf16 (fc2_w)
constexpr size_t WS_NEEDED = B_WG2 + 147456;        // 234,602,496 B

// ---------------- type helpers ----------------
__device__ __forceinline__ float ldf(const float* p) { return *p; }
__device__ __forceinline__ float ldf(const bf16* p)  { return __bfloat162float(*p); }
__device__ __forceinline__ void  stf(float* p, float v) { *p = v; }
__device__ __forceinline__ void  stf(bf16* p, float v)  { *p = __float2bfloat16(v); }
__device__ __forceinline__ unsigned short f2bf(float f) {
    unsigned u = __builtin_bit_cast(unsigned, f);
    unsigned r = (u + 0x7fffu + ((u >> 16) & 1u)) >> 16;
    return (unsigned short)r;
}
__device__ __forceinline__ float bf2f(short s) {
    unsigned u = ((unsigned)(unsigned short)s) << 16;
    return __builtin_bit_cast(float, u);
}

// ---------------- conv weight pre-pack (MFMA fragment order, bf16) ----------------
__global__ void build_wf_kernel(const float* __restrict__ w, short* __restrict__ wf) {
    int o = blockIdx.x * 256 + threadIdx.x;
    if (o >= 331776) return;
    int within = o & 511, frag = o >> 9;
    int l = within >> 3, j = within & 7;
    int nt = frag % 12, t2 = frag / 12, ks = t2 % 6, tap = t2 / 6;
    int co = nt * 16 + (l & 15);
    int ci = ks * 32 + (l >> 4) * 8 + j;
    wf[o] = (short)f2bf(w[(co * 192 + ci) * 9 + tap]);
}
// generic GEMM weight pre-pack: w is K x N row-major f32 -> frag order bf16
__global__ void build_wgemm_kernel(const float* __restrict__ w, short* __restrict__ wf,
                                   int K, int N) {
    int o = blockIdx.x * 256 + threadIdx.x;
    if (o >= K * N) return;
    int j = o & 7, l = (o >> 3) & 63, f = o >> 9;
    int ntiles = N >> 4;
    int kt = f / ntiles, nt = f % ntiles;
    int k = kt * 32 + (l >> 4) * 8 + j;
    int col = nt * 16 + (l & 15);
    wf[o] = (short)f2bf(w[(size_t)k * N + col]);
}
// conv3 1x1 pre-pack: w[co][ci] -> A-frag order (row = co)
__global__ void build_w3f_kernel(const float* __restrict__ w, short* __restrict__ wf) {
    int o = blockIdx.x * 256 + threadIdx.x;
    if (o >= 36864) return;
    int j = o & 7, l = (o >> 3) & 63, f = o >> 9;   // f = kt*12 + ct
    int kt = f / 12, ct = f % 12;
    int co = ct * 16 + (l & 15);
    int ci = kt * 32 + (l >> 4) * 8 + j;
    wf[o] = (short)f2bf(w[co * 192 + ci]);
}

// ---------------- conv3x3 (4x4 patches) + groupnorm (+silu), MFMA ----------------
// 4 patches/block, 256 threads (4 waves). Wave w owns n-tiles 3w..3w+2 (co w*48..w*48+47).
template <bool FIRST>
__global__ __launch_bounds__(256, 4) void conv_mfma_kernel(
    const float* __restrict__ src, const short* __restrict__ wf,
    const float* __restrict__ bias, const float* __restrict__ gng,
    const float* __restrict__ gnb, bf16* __restrict__ dst)
{
    __shared__ short xs[13056];          // 4 patches * 17 rows * 384B (row 16 = zeros), swizzled
    __shared__ float gsum[4][6], gsum2[4][6], gmu[4][6], grs[4][6];
    const int tid  = threadIdx.x;
    const int lane = tid & 63, wid = tid >> 6;
    const int n0   = blockIdx.x * 4;

    if (tid < 24) { gsum[tid / 6][tid % 6] = 0.f; gsum2[tid / 6][tid % 6] = 0.f; }
    for (int u = tid; u < 4 * 192; u += 256) {       // zero rows
        int q = u / 192;
        xs[q * 3264 + 3072 + (u % 192)] = 0;
    }

    const float4* sp = (const float4*)(src + (size_t)n0 * 3072);
    if (FIRST) {
        #pragma unroll
        for (int u = 0; u < 12; ++u) {
            int idx = u * 256 + tid;                 // float4 index, 3072 total
            float4 v = sp[idx];
            int q = idx / 768;
            int li = (idx % 768) * 4;                // li = ci*16 + p
            int ci = li >> 4, p0 = li & 15;
            float vv[4] = { v.x, v.y, v.z, v.w };
            #pragma unroll
            for (int k = 0; k < 4; ++k) {
                int row = p0 + k;
                int ba = q * 6528 + ((row * 384 + ci * 2) ^ ((row & 7) << 4));
                *(short*)((char*)xs + ba) = (short)f2bf(vv[k]);
            }
        }
    } else {
        #pragma unroll
        for (int u = 0; u < 12; ++u) {
            int idx = u * 256 + tid;
            float4 v = sp[idx];
            int r = idx / 48;                        // row 0..63 (token within block)
            int c0 = (idx % 48) * 4;
            int q = r >> 4, rl = r & 15;
            s4v pk = { (short)f2bf(v.x), (short)f2bf(v.y), (short)f2bf(v.z), (short)f2bf(v.w) };
            int ba = q * 6528 + ((rl * 384 + c0 * 2) ^ ((rl & 7) << 4));
            *(s4v*)((char*)xs + ba) = pk;
        }
    }
    __syncthreads();

    const int ntb = wid * 3;
    const int cl  = lane & 15;       // A-row (= output pos p) / B-col (= co within tile)
    const int kg  = lane >> 4;
    f32x4 acc[3][4];
    #pragma unroll
    for (int t = 0; t < 3; ++t) {
        float bv = bias[(ntb + t) * 16 + cl];
        #pragma unroll
        for (int q = 0; q < 4; ++q) acc[t][q] = (f32x4){ bv, bv, bv, bv };
    }

    const int pi = cl >> 2, pj = cl & 3;
    const s8v* wf8 = (const s8v*)wf;

    for (int tap = 0; tap < 9; ++tap) {
        const int di = tap / 3, dj = tap % 3;
        const int ii = pi + di - 1, jj = pj + dj - 1;
        const bool valid = (ii >= 0 && ii < 4 && jj >= 0 && jj < 4);
        const int nr  = valid ? (ii * 4 + jj) : 16;   // row 16 = zero row
        const int rb  = nr * 384;
        const int swz = (nr & 7) << 4;
        #pragma unroll
        for (int ks = 0; ks < 6; ++ks) {
            const s8v* bp = wf8 + (size_t)((tap * 6 + ks) * 12) * 64 + lane;
            s8v b0 = bp[(ntb + 0) * 64];
            s8v b1 = bp[(ntb + 1) * 64];
            s8v b2 = bp[(ntb + 2) * 64];
            const int inner = (rb + ks * 64 + kg * 16) ^ swz;
            #pragma unroll
            for (int q = 0; q < 4; ++q) {
                s8v a = *(const s8v*)((const char*)xs + q * 6528 + inner);
                acc[0][q] = __builtin_amdgcn_mfma_f32_16x16x32_bf16(a, b0, acc[0][q], 0, 0, 0);
                acc[1][q] = __builtin_amdgcn_mfma_f32_16x16x32_bf16(a, b1, acc[1][q], 0, 0, 0);
                acc[2][q] = __builtin_amdgcn_mfma_f32_16x16x32_bf16(a, b2, acc[2][q], 0, 0, 0);
            }
        }
    }

    #pragma unroll
    for (int t = 0; t < 3; ++t) {
        const int g = (ntb + t) >> 1;
        #pragma unroll
        for (int q = 0; q < 4; ++q) {
            f32x4 A = acc[t][q];
            float s  = A[0] + A[1] + A[2] + A[3];
            float s2 = A[0]*A[0] + A[1]*A[1] + A[2]*A[2] + A[3]*A[3];
            #pragma unroll
            for (int off = 32; off; off >>= 1) { s += __shfl_xor(s, off); s2 += __shfl_xor(s2, off); }
            if (lane == 0) { atomicAdd(&gsum[q][g], s); atomicAdd(&gsum2[q][g], s2); }
        }
    }
    __syncthreads();
    if (tid < 24) {
        int q = tid / 6, g = tid % 6;
        float mu  = gsum[q][g] * (1.f / 512.f);
        float var = gsum2[q][g] * (1.f / 512.f) - mu * mu;
        gmu[q][g] = mu; grs[q][g] = rsqrtf(var + 1e-5f);
    }
    __syncthreads();

    if (FIRST) {
        #pragma unroll
        for (int t = 0; t < 3; ++t) {
            const int co = (ntb + t) * 16 + cl, g = (ntb + t) >> 1;
            const float gg = gng[co], gb = gnb[co];
            #pragma unroll
            for (int q = 0; q < 4; ++q) {
                const float mu = gmu[q][g], rs = grs[q][g];
                bf16* op = dst + (((size_t)(n0 + q) * 16) + kg * 4) * 192 + co;
                #pragma unroll
                for (int r = 0; r < 4; ++r) {
                    float v = (acc[t][q][r] - mu) * rs * gg + gb;
                    v = v / (1.f + expf(-v));        // silu
                    op[(size_t)r * 192] = __float2bfloat16(v);
                }
            }
        }
    } else {
        #pragma unroll
        for (int t = 0; t < 3; ++t) {
            const int co = (ntb + t) * 16 + cl, g = (ntb + t) >> 1;
            const float gg = gng[co], gb = gnb[co];
            #pragma unroll
            for (int q = 0; q < 4; ++q) {
                const float mu = gmu[q][g], rs = grs[q][g];
                #pragma unroll
                for (int r = 0; r < 4; ++r) {
                    float v = (acc[t][q][r] - mu) * rs * gg + gb;
                    xs[q * 3072 + co * 16 + kg * 4 + r] = (short)f2bf(v);
                }
            }
        }
        __syncthreads();
        s4v* dp = (s4v*)(dst + (size_t)n0 * 3072);
        const s4v* sps = (const s4v*)xs;
        #pragma unroll
        for (int u = 0; u < 12; ++u) {
            dp[u * 256 + tid] = sps[u * 256 + tid];
        }
    }
}

// ---------------- layernorm over last dim (192), bf16 -> bf16 ----------------
__global__ __launch_bounds__(256) void ln_kernel(
    const bf16* __restrict__ in, const float* __restrict__ g,
    const float* __restrict__ bb, bf16* __restrict__ out)
{
    const int row  = blockIdx.x * 4 + (threadIdx.x >> 6);
    const int lane = threadIdx.x & 63;
    const bf16* ip = in + (size_t)row * 192;
    float v0 = ldf(&ip[lane]), v1 = ldf(&ip[lane + 64]), v2 = ldf(&ip[lane + 128]);
    float s = v0 + v1 + v2, s2 = v0 * v0 + v1 * v1 + v2 * v2;
    #pragma unroll
    for (int off = 32; off; off >>= 1) { s += __shfl_xor(s, off); s2 += __shfl_xor(s2, off); }
    const float mu  = s * (1.f / 192.f);
    const float var = s2 * (1.f / 192.f) - mu * mu;
    const float rs  = rsqrtf(var + 1e-5f);
    bf16* op = out + (size_t)row * 192;
    stf(&op[lane],       (v0 - mu) * rs * g[lane]       + bb[lane]);
    stf(&op[lane + 64],  (v1 - mu) * rs * g[lane + 64]  + bb[lane + 64]);
    stf(&op[lane + 128], (v2 - mu) * rs * g[lane + 128] + bb[lane + 128]);
}

// ---------------- MFMA GEMM, zero-LDS ----------------
template <typename TO, bool RES, bool GELU_ACT>
__global__ __launch_bounds__(256) void gemm_mfma_kernel(
    const bf16* __restrict__ A, const short* __restrict__ wfb,
    const float* __restrict__ bias, const bf16* __restrict__ res,
    TO* __restrict__ out, int K, int N)
{
    const int tid = threadIdx.x, lane = tid & 63, wid = tid >> 6;
    const int m0 = blockIdx.x * 128, n0 = blockIdx.y * 64;
    const int cl = lane & 15, kg = lane >> 4;
    const int ntiles = N >> 4, nt0 = n0 >> 4;

    f32x4 acc[2][4];
    #pragma unroll
    for (int nf = 0; nf < 4; ++nf) {
        float bv = bias[n0 + nf * 16 + cl];
        acc[0][nf] = (f32x4){ bv, bv, bv, bv };
        acc[1][nf] = (f32x4){ bv, bv, bv, bv };
    }

    const s8v* wf8 = (const s8v*)wfb;
    const int nkt = K >> 5;
    for (int kt = 0; kt < nkt; ++kt) {
        s8v a0 = *(const s8v*)(A + (size_t)(m0 + wid * 32 +      cl) * K + kt * 32 + kg * 8);
        s8v a1 = *(const s8v*)(A + (size_t)(m0 + wid * 32 + 16 + cl) * K + kt * 32 + kg * 8);
        #pragma unroll
        for (int nf = 0; nf < 4; ++nf) {
            s8v b = wf8[(size_t)(kt * ntiles + nt0 + nf) * 64 + lane];
            acc[0][nf] = __builtin_amdgcn_mfma_f32_16x16x32_bf16(a0, b, acc[0][nf], 0, 0, 0);
            acc[1][nf] = __builtin_amdgcn_mfma_f32_16x16x32_bf16(a1, b, acc[1][nf], 0, 0, 0);
        }
    }

    #pragma unroll
    for (int rf = 0; rf < 2; ++rf) {
        #pragma unroll
        for (int nf = 0; nf < 4; ++nf) {
            const int col = n0 + nf * 16 + cl;
            #pragma unroll
            for (int r = 0; r < 4; ++r) {
                const int row = m0 + wid * 32 + rf * 16 + kg * 4 + r;
                float v = acc[rf][nf][r];
                if (GELU_ACT) v = 0.5f * v * (1.f + erff(v * 0.70710678118f));
                if (RES) v += ldf(&res[(size_t)row * N + col]);
                stf(&out[(size_t)row * N + col], v);
            }
        }
    }
}

// ---------------- overlapping-window attention (f16 LDS, fdot2) ----------------
constexpr int HSTR = 1160;   // per-head LDS stride in shorts (36*32 + 8 pad)
__global__ __launch_bounds__(128) void attn_kernel(
    const bf16* __restrict__ qkv, const float* __restrict__ rpb,
    bf16* __restrict__ out)
{
    __shared__ short kh[6 * HSTR];
    __shared__ short vh[6 * HSTR];
    const int w = blockIdx.x;
    const int b = w / (NHW * NHW), wi = w % (NHW * NHW);
    const int nhi = wi / NHW, nwi = wi % NHW;
    const int tid = threadIdx.x;
    const int r0 = nhi * 4 - 1, c0 = nwi * 4 - 1;

    #pragma unroll
    for (int it = 0; it < 14; ++it) {
        int v = tid + it * 128;
        if (v < 1728) {
            int h = v / 288, rem = v % 288, kj = rem >> 3, d0 = (rem & 7) * 4;
            int rr = r0 + kj / 6, cc = c0 + kj % 6;
            s4v kvk = { 0, 0, 0, 0 }, kvv = { 0, 0, 0, 0 };
            if (rr >= 0 && rr < CH && cc >= 0 && cc < CW) {
                size_t base = ((size_t)((b * CH + rr) * CW + cc)) * 576 + h * 32 + d0;
                kvk = *(const s4v*)(qkv + base + 192);
                kvv = *(const s4v*)(qkv + base + 384);
            }
            s4v ko, vo;
            #pragma unroll
            for (int e = 0; e < 4; ++e) {
                ko[e] = __builtin_bit_cast(short, (_Float16)bf2f(kvk[e]));
                vo[e] = __builtin_bit_cast(short, (_Float16)bf2f(kvv[e]));
            }
            int off = h * HSTR + kj * 32 + d0;
            *(s4v*)(kh + off) = ko;
            *(s4v*)(vh + off) = vo;
        }
    }
    __syncthreads();

    if (tid < 96) {
        const int h = tid >> 4, qi = tid & 15;
        const int qr = nhi * 4 + (qi >> 2), qc = nwi * 4 + (qi & 3);
        const bf16* qp = qkv + ((size_t)((b * CH + qr) * CW + qc)) * 576 + h * 32;
        h2 qh[16];
        #pragma unroll
        for (int u = 0; u < 4; ++u) {
            s8v qv = *(const s8v*)(qp + u * 8);
            #pragma unroll
            for (int e = 0; e < 4; ++e) {
                h2 p;
                p[0] = (_Float16)bf2f(qv[2 * e]);
                p[1] = (_Float16)bf2f(qv[2 * e + 1]);
                qh[u * 4 + e] = p;
            }
        }

        float sc[36];
        const char* khb = (const char*)(kh + h * HSTR);
        #pragma unroll
        for (int kj = 0; kj < 36; ++kj) {
            const uint4* kp = (const uint4*)(khb + kj * 64);
            uint4 k0 = kp[0], k1 = kp[1], k2 = kp[2], k3 = kp[3];
            unsigned kwv[16] = { k0.x, k0.y, k0.z, k0.w, k1.x, k1.y, k1.z, k1.w,
                                 k2.x, k2.y, k2.z, k2.w, k3.x, k3.y, k3.z, k3.w };
            float a = 0.f;
            #pragma unroll
            for (int e = 0; e < 16; ++e)
                a = __builtin_amdgcn_fdot2(__builtin_bit_cast(h2, kwv[e]), qh[e], a, false);
            const int rel0 = kj / 6 - (qi >> 2) + 3;
            const int rel1 = kj % 6 - (qi & 3) + 3;
            sc[kj] = a * 0.17677669529f + rpb[(rel0 * 9 + rel1) * 6 + h];
        }
        float mx = -1e30f;
        #pragma unroll
        for (int kj = 0; kj < 36; ++kj) mx = fmaxf(mx, sc[kj]);
        float sum = 0.f;
        #pragma unroll
        for (int kj = 0; kj < 36; ++kj) { sc[kj] = expf(sc[kj] - mx); sum += sc[kj]; }
        const float inv = 1.f / sum;

        float o[32];
        #pragma unroll
        for (int d = 0; d < 32; ++d) o[d] = 0.f;
        const char* vhb = (const char*)(vh + h * HSTR);
        #pragma unroll
        for (int kj = 0; kj < 36; ++kj) {
            const uint4* vp = (const uint4*)(vhb + kj * 64);
            uint4 v0 = vp[0], v1 = vp[1], v2 = vp[2], v3 = vp[3];
            unsigned vwv[16] = { v0.x, v0.y, v0.z, v0.w, v1.x, v1.y, v1.z, v1.w,
                                 v2.x, v2.y, v2.z, v2.w, v3.x, v3.y, v3.z, v3.w };
            const float p = sc[kj];
            #pragma unroll
            for (int e = 0; e < 16; ++e) {
                h2 hv = __builtin_bit_cast(h2, vwv[e]);
                o[2 * e]     += p * (float)hv[0];
                o[2 * e + 1] += p * (float)hv[1];
            }
        }
        bf16* op = out + ((size_t)(b * TOKPB + qr * CW + qc)) * 192 + h * 32;
        #pragma unroll
        for (int u = 0; u < 8; ++u) {
            s4v pk;
            #pragma unroll
            for (int e = 0; e < 4; ++e) pk[e] = (short)f2bf(o[u * 4 + e] * inv);
            *(s4v*)((bf16*)op + u * 4) = pk;
        }
    }
}

// ---------------- final: out = relu(C2 + conv1x1(x)), MFMA ----------------
// block: 64 pixels x 192 co for one batch; A = w3 frags (L2), B = x staged in LDS.
__global__ __launch_bounds__(256, 4) void final_mfma_kernel(
    const float* __restrict__ x, const short* __restrict__ w3f,
    const float* __restrict__ b3, const bf16* __restrict__ c2,
    float* __restrict__ out)
{
    __shared__ short xs2[12288];      // [64 pix][192 ci] bf16, row-swizzled; 24576 B
    const int pix0 = blockIdx.x * 64;
    const int b    = blockIdx.y;
    const int tid = threadIdx.x, lane = tid & 63, wid = tid >> 6;
    const int cl = lane & 15, kg = lane >> 4;
    const float* xb = x + (size_t)b * (192 * TOKPB);

    #pragma unroll
    for (int u = 0; u < 12; ++u) {
        int idx = u * 256 + tid;                  // 3072 float4
        int ci = idx >> 4, p4 = (idx & 15) << 2;
        float4 v = *(const float4*)(xb + (size_t)ci * TOKPB + pix0 + p4);
        float vv[4] = { v.x, v.y, v.z, v.w };
        #pragma unroll
        for (int k = 0; k < 4; ++k) {
            int row = p4 + k;
            int ba = (row * 384 + ci * 2) ^ ((row & 7) << 4);
            *(short*)((char*)xs2 + ba) = (short)f2bf(vv[k]);
        }
    }
    __syncthreads();

    const int ctb = wid * 3;
    f32x4 acc[3][4] = {};
    const s8v* wf8 = (const s8v*)w3f;

    #pragma unroll
    for (int kt = 0; kt < 6; ++kt) {
        s8v a0 = wf8[(size_t)(kt * 12 + ctb + 0) * 64 + lane];
        s8v a1 = wf8[(size_t)(kt * 12 + ctb + 1) * 64 + lane];
        s8v a2 = wf8[(size_t)(kt * 12 + ctb + 2) * 64 + lane];
        #pragma unroll
        for (int pt = 0; pt < 4; ++pt) {
            int row = pt * 16 + cl;
            int ba = (row * 384 + kt * 64 + kg * 16) ^ ((row & 7) << 4);
            s8v bfr = *(const s8v*)((const char*)xs2 + ba);
            acc[0][pt] = __builtin_amdgcn_mfma_f32_16x16x32_bf16(a0, bfr, acc[0][pt], 0, 0, 0);
            acc[1][pt] = __builtin_amdgcn_mfma_f32_16x16x32_bf16(a1, bfr, acc[1][pt], 0, 0, 0);
            acc[2][pt] = __builtin_amdgcn_mfma_f32_16x16x32_bf16(a2, bfr, acc[2][pt], 0, 0, 0);
        }
    }

    #pragma unroll
    for (int t = 0; t < 3; ++t) {
        #pragma unroll
        for (int r = 0; r < 4; ++r) {
            const int co = (ctb + t) * 16 + kg * 4 + r;
            const float bb = b3[co];
            const size_t rowbase = (size_t)b * (192 * TOKPB) + (size_t)co * TOKPB + pix0;
            #pragma unroll
            for (int pt = 0; pt < 4; ++pt) {
                const size_t f = rowbase + pt * 16 + cl;
                float v = acc[t][pt][r] + bb + bf2f(__builtin_bit_cast(short, c2[f]));
                out[f] = fmaxf(v, 0.f);
            }
        }
    }
}

// ---------------- host launch ----------------
extern "C" void kernel_launch(void* const* d_in, const int* in_sizes, int n_in,
                              void* d_out, int out_size, void* d_ws, size_t ws_size,
                              hipStream_t stream)
{
    if (ws_size < WS_NEEDED) return;

    const float* x       = (const float*)d_in[0];
    const float* conv1_w = (const float*)d_in[1];
    const float* conv1_b = (const float*)d_in[2];
    const float* gn1_g   = (const float*)d_in[3];
    const float* gn1_b   = (const float*)d_in[4];
    const float* conv2_w = (const float*)d_in[5];
    const float* conv2_b = (const float*)d_in[6];
    const float* gn2_g   = (const float*)d_in[7];
    const float* gn2_b   = (const float*)d_in[8];
    const float* conv3_w = (const float*)d_in[9];
    const float* conv3_b = (const float*)d_in[10];
    const float* ln1_g   = (const float*)d_in[11];
    const float* ln1_b   = (const float*)d_in[12];
    const float* qkv_w   = (const float*)d_in[13];
    const float* qkv_b   = (const float*)d_in[14];
    const float* rpb     = (const float*)d_in[15];
    const float* proj_w  = (const float*)d_in[16];
    const float* proj_b  = (const float*)d_in[17];
    const float* ln2_g   = (const float*)d_in[18];
    const float* ln2_b   = (const float*)d_in[19];
    const float* fc1_w   = (const float*)d_in[20];
    const float* fc1_b   = (const float*)d_in[21];
    const float* fc2_w   = (const float*)d_in[22];
    const float* fc2_b   = (const float*)d_in[23];

    char* wsb = (char*)d_ws;
    bf16*  T0  = (bf16*)(wsb + B_T0);
    bf16*  P2  = (bf16*)(wsb + B_P2);
    bf16*  P3  = (bf16*)(wsb + B_P3);
    bf16*  P4  = (bf16*)(wsb + B_P4);
    short* WF1 = (short*)(wsb + B_WF1);
    short* WF2 = (short*)(wsb + B_WF2);
    short* W3F = (short*)(wsb + B_W3F);
    short* WQ  = (short*)(wsb + B_WQ);
    short* WP  = (short*)(wsb + B_WP);
    short* WG1 = (short*)(wsb + B_WG1);
    short* WG2 = (short*)(wsb + B_WG2);
    float* OUT = (float*)d_out;

    // weight prep
    build_wf_kernel<<<(331776 + 255) / 256, 256, 0, stream>>>(conv1_w, WF1);
    build_wf_kernel<<<(331776 + 255) / 256, 256, 0, stream>>>(conv2_w, WF2);
    build_w3f_kernel<<<(36864 + 255) / 256, 256, 0, stream>>>(conv3_w, W3F);
    build_wgemm_kernel<<<(110592 + 255) / 256, 256, 0, stream>>>(qkv_w, WQ, 192, 576);
    build_wgemm_kernel<<<(36864 + 255) / 256, 256, 0, stream>>>(proj_w, WP, 192, 192);
    build_wgemm_kernel<<<(73728 + 255) / 256, 256, 0, stream>>>(fc1_w, WG1, 192, 384);
    build_wgemm_kernel<<<(73728 + 255) / 256, 256, 0, stream>>>(fc2_w, WG2, 384, 192);

    // stage A: conv1 + gn1 + silu -> T0 (token layout, bf16)
    conv_mfma_kernel<true><<<NPATCH / 4, 256, 0, stream>>>(x, WF1, conv1_b, gn1_g, gn1_b, T0);
    // stage B: LN1 -> P3 (XN)
    ln_kernel<<<MTOK / 4, 256, 0, stream>>>(T0, ln1_g, ln1_b, P3);
    // stage C: qkv gemm -> P2 (QKV)
    gemm_mfma_kernel<bf16, false, false><<<dim3(MTOK / 128, 9), 256, 0, stream>>>(P3, WQ, qkv_b, nullptr, P2, 192, 576);
    // stage D: attention -> P3 (ATT)
    attn_kernel<<<NPATCH, 128, 0, stream>>>(P2, rpb, P3);
    // stage E: proj + shortcut(T0) -> P4 (OMID)
    gemm_mfma_kernel<bf16, true, false><<<dim3(MTOK / 128, 3), 256, 0, stream>>>(P3, WP, proj_b, T0, P4, 192, 192);
    // stage F: LN2 -> P3 (XM)
    ln_kernel<<<MTOK / 4, 256, 0, stream>>>(P4, ln2_g, ln2_b, P3);
    // stage G: fc1 + gelu -> P2 (HID)
    gemm_mfma_kernel<bf16, false, true><<<dim3(MTOK / 128, 6), 256, 0, stream>>>(P3, WG1, fc1_b, nullptr, P2, 192, 384);
    // stage H: fc2 + residual(OMID) -> d_out (OCAB, token layout, f32)
    gemm_mfma_kernel<float, true, false><<<dim3(MTOK / 128, 3), 256, 0, stream>>>(P2, WG2, fc2_b, P4, OUT, 384, 192);
    // stage I: conv2 + gn2 (reads d_out token layout) -> P4 (C2, bf16 patch-flat)
    conv_mfma_kernel<false><<<NPATCH / 4, 256, 0, stream>>>(OUT, WF2, conv2_b, gn2_g, gn2_b, P4);
    // stage J: out = relu(C2 + conv1x1(x)) -> d_out, MFMA
    final_mfma_kernel<<<dim3(TOKPB / 64, CB), 256, 0, stream>>>(x, W3F, conv3_b, P4, OUT);
}

// Round 6
// 620.068 us; speedup vs baseline: 5.3147x; 1.0055x over previous
//
#include <hip/hip_runtime.h>
#include <hip/hip_bf16.h>
#include <math.h>

typedef __hip_bfloat16 bf16;
typedef __attribute__((ext_vector_type(8))) short s8v;
typedef __attribute__((ext_vector_type(4))) short s4v;
typedef __attribute__((ext_vector_type(4))) float f32x4;
typedef __attribute__((ext_vector_type(2))) _Float16 h2;

// ---------------- problem constants ----------------
constexpr int CB   = 2;            // batch
constexpr int CH   = 224, CW = 224;
constexpr int NHW  = 56;           // H/WS
constexpr int NPATCH = CB * NHW * NHW;   // 6272
constexpr int TOKPB  = CH * CW;          // 50176 tokens per batch
constexpr int MTOK   = CB * TOKPB;       // 100352 rows

// ---------------- ws layout (BYTE offsets) ----------------
constexpr size_t B_T0  = 0;                         // 19267584 bf16
constexpr size_t B_P2  = B_T0 + 38535168;           // 57802752 bf16 (QKV; later HID)
constexpr size_t B_P3  = B_P2 + 115605504;          // 19267584 bf16 (ATT -> OCAB)
constexpr size_t B_P4  = B_P3 + 38535168;           // 19267584 bf16 (OMID -> C2)
constexpr size_t B_WF1 = B_P4 + 38535168;           // conv1 frag weights
constexpr size_t B_WF2 = B_WF1 + 1327104;           // conv2 frag weights
constexpr size_t B_W3F = B_WF2 + 1327104;           // conv3 1x1 frag weights
constexpr size_t B_WQ  = B_W3F + 147456;            // qkv_w frag
constexpr size_t B_WP  = B_WQ + 221184;             // proj_w frag
constexpr size_t B_WG1 = B_WP + 73728;              // fc1_w frag
constexpr size_t B_WG2 = B_WG1 + 147456;            // fc2_w frag
constexpr size_t WS_NEEDED = B_WG2 + 147456;        // 234,602,496 B

// ---------------- type helpers ----------------
__device__ __forceinline__ float ldf(const float* p) { return *p; }
__device__ __forceinline__ float ldf(const bf16* p)  { return __bfloat162float(*p); }
__device__ __forceinline__ void  stf(float* p, float v) { *p = v; }
__device__ __forceinline__ void  stf(bf16* p, float v)  { *p = __float2bfloat16(v); }
__device__ __forceinline__ unsigned short f2bf(float f) {
    unsigned u = __builtin_bit_cast(unsigned, f);
    unsigned r = (u + 0x7fffu + ((u >> 16) & 1u)) >> 16;
    return (unsigned short)r;
}
__device__ __forceinline__ float bf2f(short s) {
    unsigned u = ((unsigned)(unsigned short)s) << 16;
    return __builtin_bit_cast(float, u);
}

// ---------------- weight pre-pack kernels ----------------
__global__ void build_wf_kernel(const float* __restrict__ w, short* __restrict__ wf) {
    int o = blockIdx.x * 256 + threadIdx.x;
    if (o >= 331776) return;
    int within = o & 511, frag = o >> 9;
    int l = within >> 3, j = within & 7;
    int nt = frag % 12, t2 = frag / 12, ks = t2 % 6, tap = t2 / 6;
    int co = nt * 16 + (l & 15);
    int ci = ks * 32 + (l >> 4) * 8 + j;
    wf[o] = (short)f2bf(w[(co * 192 + ci) * 9 + tap]);
}
__global__ void build_wgemm_kernel(const float* __restrict__ w, short* __restrict__ wf,
                                   int K, int N) {
    int o = blockIdx.x * 256 + threadIdx.x;
    if (o >= K * N) return;
    int j = o & 7, l = (o >> 3) & 63, f = o >> 9;
    int ntiles = N >> 4;
    int kt = f / ntiles, nt = f % ntiles;
    int k = kt * 32 + (l >> 4) * 8 + j;
    int col = nt * 16 + (l & 15);
    wf[o] = (short)f2bf(w[(size_t)k * N + col]);
}
__global__ void build_w3f_kernel(const float* __restrict__ w, short* __restrict__ wf) {
    int o = blockIdx.x * 256 + threadIdx.x;
    if (o >= 36864) return;
    int j = o & 7, l = (o >> 3) & 63, f = o >> 9;   // f = kt*12 + ct
    int kt = f / 12, ct = f % 12;
    int co = ct * 16 + (l & 15);
    int ci = kt * 32 + (l >> 4) * 8 + j;
    wf[o] = (short)f2bf(w[co * 192 + ci]);
}

// ---------------- conv3x3 (4x4 patches) + groupnorm (+silu), MFMA ----------------
// FIRST=true : src f32 patch-flat (x), dst bf16 token layout, SiLU
// FIRST=false: src bf16 token layout, dst bf16 patch-flat
template <bool FIRST>
__global__ __launch_bounds__(256, 4) void conv_mfma_kernel(
    const void* __restrict__ srcv, const short* __restrict__ wf,
    const float* __restrict__ bias, const float* __restrict__ gng,
    const float* __restrict__ gnb, bf16* __restrict__ dst)
{
    __shared__ short xs[13056];          // 4 patches * 17 rows * 384B (row 16 = zeros), swizzled
    __shared__ float gsum[4][6], gsum2[4][6], gmu[4][6], grs[4][6];
    const int tid  = threadIdx.x;
    const int lane = tid & 63, wid = tid >> 6;
    const int n0   = blockIdx.x * 4;

    if (tid < 24) { gsum[tid / 6][tid % 6] = 0.f; gsum2[tid / 6][tid % 6] = 0.f; }
    for (int u = tid; u < 4 * 192; u += 256) {       // zero rows
        int q = u / 192;
        xs[q * 3264 + 3072 + (u % 192)] = 0;
    }

    if constexpr (FIRST) {
        const float4* sp = (const float4*)((const float*)srcv + (size_t)n0 * 3072);
        #pragma unroll
        for (int u = 0; u < 12; ++u) {
            int idx = u * 256 + tid;                 // float4 index, 3072 total
            float4 v = sp[idx];
            int q = idx / 768;
            int li = (idx % 768) * 4;                // li = ci*16 + p
            int ci = li >> 4, p0 = li & 15;
            float vv[4] = { v.x, v.y, v.z, v.w };
            #pragma unroll
            for (int k = 0; k < 4; ++k) {
                int row = p0 + k;
                int ba = q * 6528 + ((row * 384 + ci * 2) ^ ((row & 7) << 4));
                *(short*)((char*)xs + ba) = (short)f2bf(vv[k]);
            }
        }
    } else {
        const s8v* sp8 = (const s8v*)((const bf16*)srcv + (size_t)n0 * 3072);
        #pragma unroll
        for (int u = 0; u < 6; ++u) {
            int li = u * 256 + tid;                  // 1536 s8v units
            int r = li / 24, ch = li % 24;
            int q = r >> 4, rl = r & 15;
            s8v val = sp8[li];
            int ba = q * 6528 + ((rl * 384 + ch * 16) ^ ((rl & 7) << 4));
            *(s8v*)((char*)xs + ba) = val;
        }
    }
    __syncthreads();

    const int ntb = wid * 3;
    const int cl  = lane & 15;       // A-row (= output pos p) / B-col (= co within tile)
    const int kg  = lane >> 4;
    f32x4 acc[3][4];
    #pragma unroll
    for (int t = 0; t < 3; ++t) {
        float bv = bias[(ntb + t) * 16 + cl];
        #pragma unroll
        for (int q = 0; q < 4; ++q) acc[t][q] = (f32x4){ bv, bv, bv, bv };
    }

    const int pi = cl >> 2, pj = cl & 3;
    const s8v* wf8 = (const s8v*)wf;

    for (int tap = 0; tap < 9; ++tap) {
        const int di = tap / 3, dj = tap % 3;
        const int ii = pi + di - 1, jj = pj + dj - 1;
        const bool valid = (ii >= 0 && ii < 4 && jj >= 0 && jj < 4);
        const int nr  = valid ? (ii * 4 + jj) : 16;   // row 16 = zero row
        const int rb  = nr * 384;
        const int swz = (nr & 7) << 4;
        #pragma unroll
        for (int ks = 0; ks < 6; ++ks) {
            const s8v* bp = wf8 + (size_t)((tap * 6 + ks) * 12) * 64 + lane;
            s8v b0 = bp[(ntb + 0) * 64];
            s8v b1 = bp[(ntb + 1) * 64];
            s8v b2 = bp[(ntb + 2) * 64];
            const int inner = (rb + ks * 64 + kg * 16) ^ swz;
            #pragma unroll
            for (int q = 0; q < 4; ++q) {
                s8v a = *(const s8v*)((const char*)xs + q * 6528 + inner);
                acc[0][q] = __builtin_amdgcn_mfma_f32_16x16x32_bf16(a, b0, acc[0][q], 0, 0, 0);
                acc[1][q] = __builtin_amdgcn_mfma_f32_16x16x32_bf16(a, b1, acc[1][q], 0, 0, 0);
                acc[2][q] = __builtin_amdgcn_mfma_f32_16x16x32_bf16(a, b2, acc[2][q], 0, 0, 0);
            }
        }
    }

    #pragma unroll
    for (int t = 0; t < 3; ++t) {
        const int g = (ntb + t) >> 1;
        #pragma unroll
        for (int q = 0; q < 4; ++q) {
            f32x4 A = acc[t][q];
            float s  = A[0] + A[1] + A[2] + A[3];
            float s2 = A[0]*A[0] + A[1]*A[1] + A[2]*A[2] + A[3]*A[3];
            #pragma unroll
            for (int off = 32; off; off >>= 1) { s += __shfl_xor(s, off); s2 += __shfl_xor(s2, off); }
            if (lane == 0) { atomicAdd(&gsum[q][g], s); atomicAdd(&gsum2[q][g], s2); }
        }
    }
    __syncthreads();
    if (tid < 24) {
        int q = tid / 6, g = tid % 6;
        float mu  = gsum[q][g] * (1.f / 512.f);
        float var = gsum2[q][g] * (1.f / 512.f) - mu * mu;
        gmu[q][g] = mu; grs[q][g] = rsqrtf(var + 1e-5f);
    }
    __syncthreads();

    if constexpr (FIRST) {
        #pragma unroll
        for (int t = 0; t < 3; ++t) {
            const int co = (ntb + t) * 16 + cl, g = (ntb + t) >> 1;
            const float gg = gng[co], gb = gnb[co];
            #pragma unroll
            for (int q = 0; q < 4; ++q) {
                const float mu = gmu[q][g], rs = grs[q][g];
                bf16* op = dst + (((size_t)(n0 + q) * 16) + kg * 4) * 192 + co;
                #pragma unroll
                for (int r = 0; r < 4; ++r) {
                    float v = (acc[t][q][r] - mu) * rs * gg + gb;
                    v = v / (1.f + expf(-v));        // silu
                    op[(size_t)r * 192] = __float2bfloat16(v);
                }
            }
        }
    } else {
        #pragma unroll
        for (int t = 0; t < 3; ++t) {
            const int co = (ntb + t) * 16 + cl, g = (ntb + t) >> 1;
            const float gg = gng[co], gb = gnb[co];
            #pragma unroll
            for (int q = 0; q < 4; ++q) {
                const float mu = gmu[q][g], rs = grs[q][g];
                #pragma unroll
                for (int r = 0; r < 4; ++r) {
                    float v = (acc[t][q][r] - mu) * rs * gg + gb;
                    xs[q * 3072 + co * 16 + kg * 4 + r] = (short)f2bf(v);
                }
            }
        }
        __syncthreads();
        s4v* dp = (s4v*)(dst + (size_t)n0 * 3072);
        const s4v* sps = (const s4v*)xs;
        #pragma unroll
        for (int u = 0; u < 12; ++u) {
            dp[u * 256 + tid] = sps[u * 256 + tid];
        }
    }
}

// ---------------- MFMA GEMM, zero-LDS, optional fused input-LN ----------------
// 256 thr = 4 waves; block tile 128x64. LN=true requires K==192.
template <typename TO, bool RES, bool GELU_ACT, bool LN>
__global__ __launch_bounds__(256) void gemm_mfma_kernel(
    const bf16* __restrict__ A, const short* __restrict__ wfb,
    const float* __restrict__ bias, const bf16* __restrict__ res,
    TO* __restrict__ out, int K, int N,
    const float* __restrict__ lng, const float* __restrict__ lnb)
{
    const int tid = threadIdx.x, lane = tid & 63, wid = tid >> 6;
    const int m0 = blockIdx.x * 128, n0 = blockIdx.y * 64;
    const int cl = lane & 15, kg = lane >> 4;
    const int ntiles = N >> 4, nt0 = n0 >> 4;

    f32x4 acc[2][4];
    #pragma unroll
    for (int nf = 0; nf < 4; ++nf) {
        float bv = bias[n0 + nf * 16 + cl];
        acc[0][nf] = (f32x4){ bv, bv, bv, bv };
        acc[1][nf] = (f32x4){ bv, bv, bv, bv };
    }

    const s8v* wf8 = (const s8v*)wfb;

    if constexpr (LN) {
        s8v af[2][6];
        const int r0 = m0 + wid * 32 + cl;
        #pragma unroll
        for (int kt = 0; kt < 6; ++kt) {
            af[0][kt] = *(const s8v*)(A + (size_t)r0 * 192 + kt * 32 + kg * 8);
            af[1][kt] = *(const s8v*)(A + (size_t)(r0 + 16) * 192 + kt * 32 + kg * 8);
        }
        #pragma unroll
        for (int r = 0; r < 2; ++r) {
            float s = 0.f, s2 = 0.f;
            #pragma unroll
            for (int kt = 0; kt < 6; ++kt)
                #pragma unroll
                for (int j = 0; j < 8; ++j) {
                    float v = bf2f(af[r][kt][j]);
                    s += v; s2 += v * v;
                }
            s  += __shfl_xor(s, 16);  s2 += __shfl_xor(s2, 16);
            s  += __shfl_xor(s, 32);  s2 += __shfl_xor(s2, 32);
            const float mu = s * (1.f / 192.f);
            const float rs = rsqrtf(s2 * (1.f / 192.f) - mu * mu + 1e-5f);
            #pragma unroll
            for (int kt = 0; kt < 6; ++kt) {
                const float* gp = lng + kt * 32 + kg * 8;
                const float* bp = lnb + kt * 32 + kg * 8;
                #pragma unroll
                for (int j = 0; j < 8; ++j) {
                    float v = (bf2f(af[r][kt][j]) - mu) * rs * gp[j] + bp[j];
                    af[r][kt][j] = (short)f2bf(v);
                }
            }
        }
        #pragma unroll
        for (int kt = 0; kt < 6; ++kt) {
            #pragma unroll
            for (int nf = 0; nf < 4; ++nf) {
                s8v b = wf8[(size_t)(kt * ntiles + nt0 + nf) * 64 + lane];
                acc[0][nf] = __builtin_amdgcn_mfma_f32_16x16x32_bf16(af[0][kt], b, acc[0][nf], 0, 0, 0);
                acc[1][nf] = __builtin_amdgcn_mfma_f32_16x16x32_bf16(af[1][kt], b, acc[1][nf], 0, 0, 0);
            }
        }
    } else {
        const int nkt = K >> 5;
        for (int kt = 0; kt < nkt; ++kt) {
            s8v a0 = *(const s8v*)(A + (size_t)(m0 + wid * 32 +      cl) * K + kt * 32 + kg * 8);
            s8v a1 = *(const s8v*)(A + (size_t)(m0 + wid * 32 + 16 + cl) * K + kt * 32 + kg * 8);
            #pragma unroll
            for (int nf = 0; nf < 4; ++nf) {
                s8v b = wf8[(size_t)(kt * ntiles + nt0 + nf) * 64 + lane];
                acc[0][nf] = __builtin_amdgcn_mfma_f32_16x16x32_bf16(a0, b, acc[0][nf], 0, 0, 0);
                acc[1][nf] = __builtin_amdgcn_mfma_f32_16x16x32_bf16(a1, b, acc[1][nf], 0, 0, 0);
            }
        }
    }

    #pragma unroll
    for (int rf = 0; rf < 2; ++rf) {
        #pragma unroll
        for (int nf = 0; nf < 4; ++nf) {
            const int col = n0 + nf * 16 + cl;
            #pragma unroll
            for (int r = 0; r < 4; ++r) {
                const int row = m0 + wid * 32 + rf * 16 + kg * 4 + r;
                float v = acc[rf][nf][r];
                if (GELU_ACT) v = 0.5f * v * (1.f + erff(v * 0.70710678118f));
                if (RES) v += ldf(&res[(size_t)row * N + col]);
                stf(&out[(size_t)row * N + col], v);
            }
        }
    }
}

// ---------------- overlapping-window attention ----------------
// K staged f16 in LDS; V read directly from global (L2-resident) in PV loop.
constexpr int HSTR = 1160;   // per-head LDS stride in shorts (36*32 + 8 pad)
__global__ __launch_bounds__(128) void attn_kernel(
    const bf16* __restrict__ qkv, const float* __restrict__ rpb,
    bf16* __restrict__ out)
{
    __shared__ short kh[6 * HSTR];
    const int w = blockIdx.x;
    const int b = w / (NHW * NHW), wi = w % (NHW * NHW);
    const int nhi = wi / NHW, nwi = wi % NHW;
    const int tid = threadIdx.x;
    const int r0 = nhi * 4 - 1, c0 = nwi * 4 - 1;

    // stage K: 864 s8v units
    #pragma unroll
    for (int it = 0; it < 7; ++it) {
        int v = tid + it * 128;
        if (v < 864) {
            int h = v / 144, rem = v % 144, kj = rem >> 2, d0 = (rem & 3) * 8;
            int rr = r0 + kj / 6, cc = c0 + kj % 6;
            s8v kvk = { 0, 0, 0, 0, 0, 0, 0, 0 };
            if (rr >= 0 && rr < CH && cc >= 0 && cc < CW) {
                size_t base = ((size_t)((b * CH + rr) * CW + cc)) * 576 + h * 32 + d0;
                kvk = *(const s8v*)(qkv + base + 192);
            }
            s8v ko;
            #pragma unroll
            for (int e = 0; e < 8; ++e)
                ko[e] = __builtin_bit_cast(short, (_Float16)bf2f(kvk[e]));
            *(s8v*)(kh + h * HSTR + kj * 32 + d0) = ko;
        }
    }
    __syncthreads();

    if (tid < 96) {
        const int h = tid >> 4, qi = tid & 15;
        const int qr = nhi * 4 + (qi >> 2), qc = nwi * 4 + (qi & 3);
        const bf16* qp = qkv + ((size_t)((b * CH + qr) * CW + qc)) * 576 + h * 32;
        h2 qh[16];
        #pragma unroll
        for (int u = 0; u < 4; ++u) {
            s8v qv = *(const s8v*)(qp + u * 8);
            #pragma unroll
            for (int e = 0; e < 4; ++e) {
                h2 p;
                p[0] = (_Float16)bf2f(qv[2 * e]);
                p[1] = (_Float16)bf2f(qv[2 * e + 1]);
                qh[u * 4 + e] = p;
            }
        }

        float sc[36];
        const char* khb = (const char*)(kh + h * HSTR);
        #pragma unroll
        for (int kj = 0; kj < 36; ++kj) {
            const uint4* kp = (const uint4*)(khb + kj * 64);
            uint4 k0 = kp[0], k1 = kp[1], k2 = kp[2], k3 = kp[3];
            unsigned kwv[16] = { k0.x, k0.y, k0.z, k0.w, k1.x, k1.y, k1.z, k1.w,
                                 k2.x, k2.y, k2.z, k2.w, k3.x, k3.y, k3.z, k3.w };
            float a = 0.f;
            #pragma unroll
            for (int e = 0; e < 16; ++e)
                a = __builtin_amdgcn_fdot2(__builtin_bit_cast(h2, kwv[e]), qh[e], a, false);
            const int rel0 = kj / 6 - (qi >> 2) + 3;
            const int rel1 = kj % 6 - (qi & 3) + 3;
            sc[kj] = a * 0.17677669529f + rpb[(rel0 * 9 + rel1) * 6 + h];
        }
        float mx = -1e30f;
        #pragma unroll
        for (int kj = 0; kj < 36; ++kj) mx = fmaxf(mx, sc[kj]);
        float sum = 0.f;
        #pragma unroll
        for (int kj = 0; kj < 36; ++kj) { sc[kj] = expf(sc[kj] - mx); sum += sc[kj]; }
        const float inv = 1.f / sum;

        float o[32];
        #pragma unroll
        for (int d = 0; d < 32; ++d) o[d] = 0.f;
        #pragma unroll
        for (int kj = 0; kj < 36; ++kj) {
            const int rr = r0 + kj / 6, cc = c0 + kj % 6;
            if (rr < 0 || rr >= CH || cc < 0 || cc >= CW) continue;   // V row is zero
            const uint4* vp = (const uint4*)(qkv + ((size_t)((b * CH + rr) * CW + cc)) * 576 + 384 + h * 32);
            uint4 v0 = vp[0], v1 = vp[1], v2 = vp[2], v3 = vp[3];
            unsigned vwv[16] = { v0.x, v0.y, v0.z, v0.w, v1.x, v1.y, v1.z, v1.w,
                                 v2.x, v2.y, v2.z, v2.w, v3.x, v3.y, v3.z, v3.w };
            const float p = sc[kj];
            #pragma unroll
            for (int e = 0; e < 16; ++e) {
                float lo = __builtin_bit_cast(float, vwv[e] << 16);
                float hi = __builtin_bit_cast(float, vwv[e] & 0xffff0000u);
                o[2 * e]     += p * lo;
                o[2 * e + 1] += p * hi;
            }
        }
        bf16* op = out + ((size_t)(b * TOKPB + qr * CW + qc)) * 192 + h * 32;
        #pragma unroll
        for (int u = 0; u < 8; ++u) {
            s4v pk;
            #pragma unroll
            for (int e = 0; e < 4; ++e) pk[e] = (short)f2bf(o[u * 4 + e] * inv);
            *(s4v*)((bf16*)op + u * 4) = pk;
        }
    }
}

// ---------------- final: out = relu(C2 + conv1x1(x)), MFMA ----------------
__global__ __launch_bounds__(256, 4) void final_mfma_kernel(
    const float* __restrict__ x, const short* __restrict__ w3f,
    const float* __restrict__ b3, const bf16* __restrict__ c2,
    float* __restrict__ out)
{
    __shared__ short xs2[12288];      // [64 pix][192 ci] bf16, row-swizzled
    const int pix0 = blockIdx.x * 64;
    const int b    = blockIdx.y;
    const int tid = threadIdx.x, lane = tid & 63, wid = tid >> 6;
    const int cl = lane & 15, kg = lane >> 4;
    const float* xb = x + (size_t)b * (192 * TOKPB);

    #pragma unroll
    for (int u = 0; u < 12; ++u) {
        int idx = u * 256 + tid;                  // 3072 float4
        int ci = idx >> 4, p4 = (idx & 15) << 2;
        float4 v = *(const float4*)(xb + (size_t)ci * TOKPB + pix0 + p4);
        float vv[4] = { v.x, v.y, v.z, v.w };
        #pragma unroll
        for (int k = 0; k < 4; ++k) {
            int row = p4 + k;
            int ba = (row * 384 + ci * 2) ^ ((row & 7) << 4);
            *(short*)((char*)xs2 + ba) = (short)f2bf(vv[k]);
        }
    }
    __syncthreads();

    const int ctb = wid * 3;
    f32x4 acc[3][4] = {};
    const s8v* wf8 = (const s8v*)w3f;

    #pragma unroll
    for (int kt = 0; kt < 6; ++kt) {
        s8v a0 = wf8[(size_t)(kt * 12 + ctb + 0) * 64 + lane];
        s8v a1 = wf8[(size_t)(kt * 12 + ctb + 1) * 64 + lane];
        s8v a2 = wf8[(size_t)(kt * 12 + ctb + 2) * 64 + lane];
        #pragma unroll
        for (int pt = 0; pt < 4; ++pt) {
            int row = pt * 16 + cl;
            int ba = (row * 384 + kt * 64 + kg * 16) ^ ((row & 7) << 4);
            s8v bfr = *(const s8v*)((const char*)xs2 + ba);
            acc[0][pt] = __builtin_amdgcn_mfma_f32_16x16x32_bf16(a0, bfr, acc[0][pt], 0, 0, 0);
            acc[1][pt] = __builtin_amdgcn_mfma_f32_16x16x32_bf16(a1, bfr, acc[1][pt], 0, 0, 0);
            acc[2][pt] = __builtin_amdgcn_mfma_f32_16x16x32_bf16(a2, bfr, acc[2][pt], 0, 0, 0);
        }
    }

    #pragma unroll
    for (int t = 0; t < 3; ++t) {
        #pragma unroll
        for (int r = 0; r < 4; ++r) {
            const int co = (ctb + t) * 16 + kg * 4 + r;
            const float bb = b3[co];
            const size_t rowbase = (size_t)b * (192 * TOKPB) + (size_t)co * TOKPB + pix0;
            #pragma unroll
            for (int pt = 0; pt < 4; ++pt) {
                const size_t f = rowbase + pt * 16 + cl;
                float v = acc[t][pt][r] + bb + bf2f(__builtin_bit_cast(short, c2[f]));
                out[f] = fmaxf(v, 0.f);
            }
        }
    }
}

// ---------------- host launch ----------------
extern "C" void kernel_launch(void* const* d_in, const int* in_sizes, int n_in,
                              void* d_out, int out_size, void* d_ws, size_t ws_size,
                              hipStream_t stream)
{
    if (ws_size < WS_NEEDED) return;

    const float* x       = (const float*)d_in[0];
    const float* conv1_w = (const float*)d_in[1];
    const float* conv1_b = (const float*)d_in[2];
    const float* gn1_g   = (const float*)d_in[3];
    const float* gn1_b   = (const float*)d_in[4];
    const float* conv2_w = (const float*)d_in[5];
    const float* conv2_b = (const float*)d_in[6];
    const float* gn2_g   = (const float*)d_in[7];
    const float* gn2_b   = (const float*)d_in[8];
    const float* conv3_w = (const float*)d_in[9];
    const float* conv3_b = (const float*)d_in[10];
    const float* ln1_g   = (const float*)d_in[11];
    const float* ln1_b   = (const float*)d_in[12];
    const float* qkv_w   = (const float*)d_in[13];
    const float* qkv_b   = (const float*)d_in[14];
    const float* rpb     = (const float*)d_in[15];
    const float* proj_w  = (const float*)d_in[16];
    const float* proj_b  = (const float*)d_in[17];
    const float* ln2_g   = (const float*)d_in[18];
    const float* ln2_b   = (const float*)d_in[19];
    const float* fc1_w   = (const float*)d_in[20];
    const float* fc1_b   = (const float*)d_in[21];
    const float* fc2_w   = (const float*)d_in[22];
    const float* fc2_b   = (const float*)d_in[23];

    char* wsb = (char*)d_ws;
    bf16*  T0  = (bf16*)(wsb + B_T0);
    bf16*  P2  = (bf16*)(wsb + B_P2);
    bf16*  P3  = (bf16*)(wsb + B_P3);
    bf16*  P4  = (bf16*)(wsb + B_P4);
    short* WF1 = (short*)(wsb + B_WF1);
    short* WF2 = (short*)(wsb + B_WF2);
    short* W3F = (short*)(wsb + B_W3F);
    short* WQ  = (short*)(wsb + B_WQ);
    short* WP  = (short*)(wsb + B_WP);
    short* WG1 = (short*)(wsb + B_WG1);
    short* WG2 = (short*)(wsb + B_WG2);
    float* OUT = (float*)d_out;

    // weight prep
    build_wf_kernel<<<(331776 + 255) / 256, 256, 0, stream>>>(conv1_w, WF1);
    build_wf_kernel<<<(331776 + 255) / 256, 256, 0, stream>>>(conv2_w, WF2);
    build_w3f_kernel<<<(36864 + 255) / 256, 256, 0, stream>>>(conv3_w, W3F);
    build_wgemm_kernel<<<(110592 + 255) / 256, 256, 0, stream>>>(qkv_w, WQ, 192, 576);
    build_wgemm_kernel<<<(36864 + 255) / 256, 256, 0, stream>>>(proj_w, WP, 192, 192);
    build_wgemm_kernel<<<(73728 + 255) / 256, 256, 0, stream>>>(fc1_w, WG1, 192, 384);
    build_wgemm_kernel<<<(73728 + 255) / 256, 256, 0, stream>>>(fc2_w, WG2, 384, 192);

    // stage A: conv1 + gn1 + silu -> T0 (token layout, bf16)
    conv_mfma_kernel<true><<<NPATCH / 4, 256, 0, stream>>>(x, WF1, conv1_b, gn1_g, gn1_b, T0);
    // stage C: LN1 (fused) + qkv gemm -> P2 (QKV)
    gemm_mfma_kernel<bf16, false, false, true><<<dim3(MTOK / 128, 9), 256, 0, stream>>>(
        T0, WQ, qkv_b, nullptr, P2, 192, 576, ln1_g, ln1_b);
    // stage D: attention -> P3 (ATT)
    attn_kernel<<<NPATCH, 128, 0, stream>>>(P2, rpb, P3);
    // stage E: proj + shortcut(T0) -> P4 (OMID)
    gemm_mfma_kernel<bf16, true, false, false><<<dim3(MTOK / 128, 3), 256, 0, stream>>>(
        P3, WP, proj_b, T0, P4, 192, 192, nullptr, nullptr);
    // stage G: LN2 (fused) + fc1 + gelu -> P2 (HID)
    gemm_mfma_kernel<bf16, false, true, true><<<dim3(MTOK / 128, 6), 256, 0, stream>>>(
        P4, WG1, fc1_b, nullptr, P2, 192, 384, ln2_g, ln2_b);
    // stage H: fc2 + residual(OMID P4) -> P3 (OCAB, bf16 token layout)
    gemm_mfma_kernel<bf16, true, false, false><<<dim3(MTOK / 128, 3), 256, 0, stream>>>(
        P2, WG2, fc2_b, P4, P3, 384, 192, nullptr, nullptr);
    // stage I: conv2 + gn2 (reads P3 bf16 token layout) -> P4 (C2, bf16 patch-flat)
    conv_mfma_kernel<false><<<NPATCH / 4, 256, 0, stream>>>(P3, WF2, conv2_b, gn2_g, gn2_b, P4);
    // stage J: out = relu(C2 + conv1x1(x)) -> d_out, MFMA
    final_mfma_kernel<<<dim3(TOKPB / 64, CB), 256, 0, stream>>>(x, W3F, conv3_b, P4, OUT);
}

// Round 7
// 606.908 us; speedup vs baseline: 5.4300x; 1.0217x over previous
//
#include <hip/hip_runtime.h>
#include <hip/hip_bf16.h>
#include <math.h>

typedef __hip_bfloat16 bf16;
typedef __attribute__((ext_vector_type(8))) short s8v;
typedef __attribute__((ext_vector_type(4))) short s4v;
typedef __attribute__((ext_vector_type(4))) float f32x4;
typedef __attribute__((ext_vector_type(2))) _Float16 h2;

// ---------------- problem constants ----------------
constexpr int CB   = 2;            // batch
constexpr int CH   = 224, CW = 224;
constexpr int NHW  = 56;           // H/WS
constexpr int NPATCH = CB * NHW * NHW;   // 6272
constexpr int TOKPB  = CH * CW;          // 50176 tokens per batch
constexpr int MTOK   = CB * TOKPB;       // 100352 rows
constexpr size_t SECSZ = 19267584;       // elems per q/k/v f16 section

// ---------------- ws layout (BYTE offsets) ----------------
constexpr size_t B_T0  = 0;                         // 19267584 bf16
constexpr size_t B_P2  = B_T0 + 38535168;           // QF/KF/VF f16 (3x38.5MB); later HID bf16
constexpr size_t B_P3  = B_P2 + 115605504;          // 19267584 bf16 (ATT -> OCAB)
constexpr size_t B_P4  = B_P3 + 38535168;           // 19267584 bf16 (OMID -> C2)
constexpr size_t B_WF1 = B_P4 + 38535168;           // conv1 frag weights
constexpr size_t B_WF2 = B_WF1 + 1327104;           // conv2 frag weights
constexpr size_t B_W3F = B_WF2 + 1327104;           // conv3 1x1 frag weights
constexpr size_t B_WQ  = B_W3F + 147456;            // qkv_w frag
constexpr size_t B_WP  = B_WQ + 221184;             // proj_w frag
constexpr size_t B_WG1 = B_WP + 73728;              // fc1_w frag
constexpr size_t B_WG2 = B_WG1 + 147456;            // fc2_w frag
constexpr size_t WS_NEEDED = B_WG2 + 147456;        // 234,602,496 B

// ---------------- type helpers ----------------
__device__ __forceinline__ float ldf(const float* p) { return *p; }
__device__ __forceinline__ float ldf(const bf16* p)  { return __bfloat162float(*p); }
__device__ __forceinline__ void  stf(float* p, float v) { *p = v; }
__device__ __forceinline__ void  stf(bf16* p, float v)  { *p = __float2bfloat16(v); }
__device__ __forceinline__ unsigned short f2bf(float f) {
    unsigned u = __builtin_bit_cast(unsigned, f);
    unsigned r = (u + 0x7fffu + ((u >> 16) & 1u)) >> 16;
    return (unsigned short)r;
}
__device__ __forceinline__ float bf2f(short s) {
    unsigned u = ((unsigned)(unsigned short)s) << 16;
    return __builtin_bit_cast(float, u);
}

// ---------------- weight pre-pack kernels ----------------
__global__ void build_wf_kernel(const float* __restrict__ w, short* __restrict__ wf) {
    int o = blockIdx.x * 256 + threadIdx.x;
    if (o >= 331776) return;
    int within = o & 511, frag = o >> 9;
    int l = within >> 3, j = within & 7;
    int nt = frag % 12, t2 = frag / 12, ks = t2 % 6, tap = t2 / 6;
    int co = nt * 16 + (l & 15);
    int ci = ks * 32 + (l >> 4) * 8 + j;
    wf[o] = (short)f2bf(w[(co * 192 + ci) * 9 + tap]);
}
__global__ void build_wgemm_kernel(const float* __restrict__ w, short* __restrict__ wf,
                                   int K, int N) {
    int o = blockIdx.x * 256 + threadIdx.x;
    if (o >= K * N) return;
    int j = o & 7, l = (o >> 3) & 63, f = o >> 9;
    int ntiles = N >> 4;
    int kt = f / ntiles, nt = f % ntiles;
    int k = kt * 32 + (l >> 4) * 8 + j;
    int col = nt * 16 + (l & 15);
    wf[o] = (short)f2bf(w[(size_t)k * N + col]);
}
__global__ void build_w3f_kernel(const float* __restrict__ w, short* __restrict__ wf) {
    int o = blockIdx.x * 256 + threadIdx.x;
    if (o >= 36864) return;
    int j = o & 7, l = (o >> 3) & 63, f = o >> 9;   // f = kt*12 + ct
    int kt = f / 12, ct = f % 12;
    int co = ct * 16 + (l & 15);
    int ci = kt * 32 + (l >> 4) * 8 + j;
    wf[o] = (short)f2bf(w[co * 192 + ci]);
}

// ---------------- conv3x3 (4x4 patches) + groupnorm (+silu), MFMA ----------------
template <bool FIRST>
__global__ __launch_bounds__(256, 4) void conv_mfma_kernel(
    const void* __restrict__ srcv, const short* __restrict__ wf,
    const float* __restrict__ bias, const float* __restrict__ gng,
    const float* __restrict__ gnb, bf16* __restrict__ dst)
{
    __shared__ short xs[13056];          // 4 patches * 17 rows * 384B (row 16 = zeros), swizzled
    __shared__ float gsum[4][6], gsum2[4][6], gmu[4][6], grs[4][6];
    const int tid  = threadIdx.x;
    const int lane = tid & 63, wid = tid >> 6;
    const int n0   = blockIdx.x * 4;

    if (tid < 24) { gsum[tid / 6][tid % 6] = 0.f; gsum2[tid / 6][tid % 6] = 0.f; }
    for (int u = tid; u < 4 * 192; u += 256) {       // zero rows
        int q = u / 192;
        xs[q * 3264 + 3072 + (u % 192)] = 0;
    }

    if constexpr (FIRST) {
        const float4* sp = (const float4*)((const float*)srcv + (size_t)n0 * 3072);
        #pragma unroll
        for (int u = 0; u < 12; ++u) {
            int idx = u * 256 + tid;                 // float4 index, 3072 total
            float4 v = sp[idx];
            int q = idx / 768;
            int li = (idx % 768) * 4;                // li = ci*16 + p
            int ci = li >> 4, p0 = li & 15;
            float vv[4] = { v.x, v.y, v.z, v.w };
            #pragma unroll
            for (int k = 0; k < 4; ++k) {
                int row = p0 + k;
                int ba = q * 6528 + ((row * 384 + ci * 2) ^ ((row & 7) << 4));
                *(short*)((char*)xs + ba) = (short)f2bf(vv[k]);
            }
        }
    } else {
        const s8v* sp8 = (const s8v*)((const bf16*)srcv + (size_t)n0 * 3072);
        #pragma unroll
        for (int u = 0; u < 6; ++u) {
            int li = u * 256 + tid;                  // 1536 s8v units
            int r = li / 24, ch = li % 24;
            int q = r >> 4, rl = r & 15;
            s8v val = sp8[li];
            int ba = q * 6528 + ((rl * 384 + ch * 16) ^ ((rl & 7) << 4));
            *(s8v*)((char*)xs + ba) = val;
        }
    }
    __syncthreads();

    const int ntb = wid * 3;
    const int cl  = lane & 15;
    const int kg  = lane >> 4;
    f32x4 acc[3][4];
    #pragma unroll
    for (int t = 0; t < 3; ++t) {
        float bv = bias[(ntb + t) * 16 + cl];
        #pragma unroll
        for (int q = 0; q < 4; ++q) acc[t][q] = (f32x4){ bv, bv, bv, bv };
    }

    const int pi = cl >> 2, pj = cl & 3;
    const s8v* wf8 = (const s8v*)wf;

    for (int tap = 0; tap < 9; ++tap) {
        const int di = tap / 3, dj = tap % 3;
        const int ii = pi + di - 1, jj = pj + dj - 1;
        const bool valid = (ii >= 0 && ii < 4 && jj >= 0 && jj < 4);
        const int nr  = valid ? (ii * 4 + jj) : 16;   // row 16 = zero row
        const int rb  = nr * 384;
        const int swz = (nr & 7) << 4;
        #pragma unroll
        for (int ks = 0; ks < 6; ++ks) {
            const s8v* bp = wf8 + (size_t)((tap * 6 + ks) * 12) * 64 + lane;
            s8v b0 = bp[(ntb + 0) * 64];
            s8v b1 = bp[(ntb + 1) * 64];
            s8v b2 = bp[(ntb + 2) * 64];
            const int inner = (rb + ks * 64 + kg * 16) ^ swz;
            #pragma unroll
            for (int q = 0; q < 4; ++q) {
                s8v a = *(const s8v*)((const char*)xs + q * 6528 + inner);
                acc[0][q] = __builtin_amdgcn_mfma_f32_16x16x32_bf16(a, b0, acc[0][q], 0, 0, 0);
                acc[1][q] = __builtin_amdgcn_mfma_f32_16x16x32_bf16(a, b1, acc[1][q], 0, 0, 0);
                acc[2][q] = __builtin_amdgcn_mfma_f32_16x16x32_bf16(a, b2, acc[2][q], 0, 0, 0);
            }
        }
    }

    #pragma unroll
    for (int t = 0; t < 3; ++t) {
        const int g = (ntb + t) >> 1;
        #pragma unroll
        for (int q = 0; q < 4; ++q) {
            f32x4 A = acc[t][q];
            float s  = A[0] + A[1] + A[2] + A[3];
            float s2 = A[0]*A[0] + A[1]*A[1] + A[2]*A[2] + A[3]*A[3];
            #pragma unroll
            for (int off = 32; off; off >>= 1) { s += __shfl_xor(s, off); s2 += __shfl_xor(s2, off); }
            if (lane == 0) { atomicAdd(&gsum[q][g], s); atomicAdd(&gsum2[q][g], s2); }
        }
    }
    __syncthreads();
    if (tid < 24) {
        int q = tid / 6, g = tid % 6;
        float mu  = gsum[q][g] * (1.f / 512.f);
        float var = gsum2[q][g] * (1.f / 512.f) - mu * mu;
        gmu[q][g] = mu; grs[q][g] = rsqrtf(var + 1e-5f);
    }
    __syncthreads();

    if constexpr (FIRST) {
        #pragma unroll
        for (int t = 0; t < 3; ++t) {
            const int co = (ntb + t) * 16 + cl, g = (ntb + t) >> 1;
            const float gg = gng[co], gb = gnb[co];
            #pragma unroll
            for (int q = 0; q < 4; ++q) {
                const float mu = gmu[q][g], rs = grs[q][g];
                bf16* op = dst + (((size_t)(n0 + q) * 16) + kg * 4) * 192 + co;
                #pragma unroll
                for (int r = 0; r < 4; ++r) {
                    float v = (acc[t][q][r] - mu) * rs * gg + gb;
                    v = v / (1.f + expf(-v));        // silu
                    op[(size_t)r * 192] = __float2bfloat16(v);
                }
            }
        }
    } else {
        #pragma unroll
        for (int t = 0; t < 3; ++t) {
            const int co = (ntb + t) * 16 + cl, g = (ntb + t) >> 1;
            const float gg = gng[co], gb = gnb[co];
            #pragma unroll
            for (int q = 0; q < 4; ++q) {
                const float mu = gmu[q][g], rs = grs[q][g];
                #pragma unroll
                for (int r = 0; r < 4; ++r) {
                    float v = (acc[t][q][r] - mu) * rs * gg + gb;
                    xs[q * 3072 + co * 16 + kg * 4 + r] = (short)f2bf(v);
                }
            }
        }
        __syncthreads();
        s4v* dp = (s4v*)(dst + (size_t)n0 * 3072);
        const s4v* sps = (const s4v*)xs;
        #pragma unroll
        for (int u = 0; u < 12; ++u) {
            dp[u * 256 + tid] = sps[u * 256 + tid];
        }
    }
}

// ---------------- MFMA GEMM, zero-LDS, optional fused input-LN / qkv-split out ----
// 256 thr = 4 waves; block tile 128x64. LN requires K==192. QKVOUT: out = f16 QF base,
// sections (Q/K/V) of 192 cols each, written head-major [b][h][tok][32].
template <typename TO, bool RES, bool GELU_ACT, bool LN, bool QKVOUT>
__global__ __launch_bounds__(256) void gemm_mfma_kernel(
    const bf16* __restrict__ A, const short* __restrict__ wfb,
    const float* __restrict__ bias, const bf16* __restrict__ res,
    TO* __restrict__ out, int K, int N,
    const float* __restrict__ lng, const float* __restrict__ lnb)
{
    const int tid = threadIdx.x, lane = tid & 63, wid = tid >> 6;
    const int m0 = blockIdx.x * 128, n0 = blockIdx.y * 64;
    const int cl = lane & 15, kg = lane >> 4;
    const int ntiles = N >> 4, nt0 = n0 >> 4;

    f32x4 acc[2][4];
    #pragma unroll
    for (int nf = 0; nf < 4; ++nf) {
        float bv = bias[n0 + nf * 16 + cl];
        acc[0][nf] = (f32x4){ bv, bv, bv, bv };
        acc[1][nf] = (f32x4){ bv, bv, bv, bv };
    }

    const s8v* wf8 = (const s8v*)wfb;

    if constexpr (LN) {
        s8v af[2][6];
        const int r0 = m0 + wid * 32 + cl;
        #pragma unroll
        for (int kt = 0; kt < 6; ++kt) {
            af[0][kt] = *(const s8v*)(A + (size_t)r0 * 192 + kt * 32 + kg * 8);
            af[1][kt] = *(const s8v*)(A + (size_t)(r0 + 16) * 192 + kt * 32 + kg * 8);
        }
        #pragma unroll
        for (int r = 0; r < 2; ++r) {
            float s = 0.f, s2 = 0.f;
            #pragma unroll
            for (int kt = 0; kt < 6; ++kt)
                #pragma unroll
                for (int j = 0; j < 8; ++j) {
                    float v = bf2f(af[r][kt][j]);
                    s += v; s2 += v * v;
                }
            s  += __shfl_xor(s, 16);  s2 += __shfl_xor(s2, 16);
            s  += __shfl_xor(s, 32);  s2 += __shfl_xor(s2, 32);
            const float mu = s * (1.f / 192.f);
            const float rs = rsqrtf(s2 * (1.f / 192.f) - mu * mu + 1e-5f);
            #pragma unroll
            for (int kt = 0; kt < 6; ++kt) {
                const float* gp = lng + kt * 32 + kg * 8;
                const float* bp = lnb + kt * 32 + kg * 8;
                #pragma unroll
                for (int j = 0; j < 8; ++j) {
                    float v = (bf2f(af[r][kt][j]) - mu) * rs * gp[j] + bp[j];
                    af[r][kt][j] = (short)f2bf(v);
                }
            }
        }
        #pragma unroll
        for (int kt = 0; kt < 6; ++kt) {
            #pragma unroll
            for (int nf = 0; nf < 4; ++nf) {
                s8v b = wf8[(size_t)(kt * ntiles + nt0 + nf) * 64 + lane];
                acc[0][nf] = __builtin_amdgcn_mfma_f32_16x16x32_bf16(af[0][kt], b, acc[0][nf], 0, 0, 0);
                acc[1][nf] = __builtin_amdgcn_mfma_f32_16x16x32_bf16(af[1][kt], b, acc[1][nf], 0, 0, 0);
            }
        }
    } else {
        const int nkt = K >> 5;
        for (int kt = 0; kt < nkt; ++kt) {
            s8v a0 = *(const s8v*)(A + (size_t)(m0 + wid * 32 +      cl) * K + kt * 32 + kg * 8);
            s8v a1 = *(const s8v*)(A + (size_t)(m0 + wid * 32 + 16 + cl) * K + kt * 32 + kg * 8);
            #pragma unroll
            for (int nf = 0; nf < 4; ++nf) {
                s8v b = wf8[(size_t)(kt * ntiles + nt0 + nf) * 64 + lane];
                acc[0][nf] = __builtin_amdgcn_mfma_f32_16x16x32_bf16(a0, b, acc[0][nf], 0, 0, 0);
                acc[1][nf] = __builtin_amdgcn_mfma_f32_16x16x32_bf16(a1, b, acc[1][nf], 0, 0, 0);
            }
        }
    }

    #pragma unroll
    for (int rf = 0; rf < 2; ++rf) {
        #pragma unroll
        for (int nf = 0; nf < 4; ++nf) {
            const int col = n0 + nf * 16 + cl;
            #pragma unroll
            for (int r = 0; r < 4; ++r) {
                const int row = m0 + wid * 32 + rf * 16 + kg * 4 + r;
                float v = acc[rf][nf][r];
                if (GELU_ACT) v = 0.5f * v * (1.f + erff(v * 0.70710678118f));
                if (RES) v += ldf(&res[(size_t)row * N + col]);
                if constexpr (QKVOUT) {
                    const int sec = n0 / 192;            // block-uniform
                    const int c = col - sec * 192, h = c >> 5, d = c & 31;
                    const int bb2 = row / TOKPB, t = row - bb2 * TOKPB;
                    ((_Float16*)out)[(size_t)sec * SECSZ +
                        ((size_t)(bb2 * 6 + h) * TOKPB + t) * 32 + d] = (_Float16)v;
                } else {
                    stf(&out[(size_t)row * N + col], v);
                }
            }
        }
    }
}

// ---------------- overlapping-window attention (f16 head-major inputs) ----------------
// one block per window, 128 threads; threads 0..95 = (head, qi). K,V staged in LDS (copy).
constexpr int HSTR = 1160;   // per-head LDS stride in shorts (36*32 + 8 pad)
__global__ __launch_bounds__(128) void attn_kernel(
    const _Float16* __restrict__ qf, const float* __restrict__ rpb,
    bf16* __restrict__ out)
{
    __shared__ short kh[6 * HSTR];
    __shared__ short vh[6 * HSTR];
    const int w = blockIdx.x;
    const int b = w / (NHW * NHW), wi = w % (NHW * NHW);
    const int nhi = wi / NHW, nwi = wi % NHW;
    const int tid = threadIdx.x;
    const int r0 = nhi * 4 - 1, c0 = nwi * 4 - 1;
    const _Float16* kfb = qf + SECSZ;
    const _Float16* vfb = qf + 2 * SECSZ;

    // stage K and V: 2*864 units of 16B, pure copy (no conversion)
    #pragma unroll
    for (int it = 0; it < 14; ++it) {
        int v = tid + it * 128;
        if (v < 1728) {
            int kv = v >= 864 ? 1 : 0;
            int u = v - kv * 864;
            int h = u / 144, rem = u % 144, kj = rem >> 2, d0 = (rem & 3) * 8;
            int rr = r0 + kj / 6, cc = c0 + kj % 6;
            s8v val = { 0, 0, 0, 0, 0, 0, 0, 0 };
            if (rr >= 0 && rr < CH && cc >= 0 && cc < CW) {
                const _Float16* src = kv ? vfb : kfb;
                val = *(const s8v*)(src + ((size_t)(b * 6 + h) * TOKPB + rr * CW + cc) * 32 + d0);
            }
            short* dst = kv ? vh : kh;
            *(s8v*)(dst + h * HSTR + kj * 32 + d0) = val;
        }
    }
    __syncthreads();

    if (tid < 96) {
        const int h = tid >> 4, qi = tid & 15;
        const int qr = nhi * 4 + (qi >> 2), qc = nwi * 4 + (qi & 3);
        const _Float16* qp = qf + ((size_t)(b * 6 + h) * TOKPB + qr * CW + qc) * 32;
        h2 qh[16];
        #pragma unroll
        for (int u = 0; u < 4; ++u) {
            uint4 qa = *(const uint4*)(qp + u * 8);
            qh[u * 4 + 0] = __builtin_bit_cast(h2, qa.x);
            qh[u * 4 + 1] = __builtin_bit_cast(h2, qa.y);
            qh[u * 4 + 2] = __builtin_bit_cast(h2, qa.z);
            qh[u * 4 + 3] = __builtin_bit_cast(h2, qa.w);
        }

        float sc[36];
        const short* khb = kh + h * HSTR;
        #pragma unroll
        for (int kj = 0; kj < 36; ++kj) {
            const uint4* kp = (const uint4*)(khb + kj * 32);
            uint4 k0 = kp[0], k1 = kp[1], k2 = kp[2], k3 = kp[3];
            unsigned kwv[16] = { k0.x, k0.y, k0.z, k0.w, k1.x, k1.y, k1.z, k1.w,
                                 k2.x, k2.y, k2.z, k2.w, k3.x, k3.y, k3.z, k3.w };
            // 4 independent fdot2 chains to break serial dependency
            float a0 = 0.f, a1 = 0.f, a2 = 0.f, a3 = 0.f;
            #pragma unroll
            for (int e = 0; e < 4; ++e) {
                a0 = __builtin_amdgcn_fdot2(__builtin_bit_cast(h2, kwv[4*e+0]), qh[4*e+0], a0, false);
                a1 = __builtin_amdgcn_fdot2(__builtin_bit_cast(h2, kwv[4*e+1]), qh[4*e+1], a1, false);
                a2 = __builtin_amdgcn_fdot2(__builtin_bit_cast(h2, kwv[4*e+2]), qh[4*e+2], a2, false);
                a3 = __builtin_amdgcn_fdot2(__builtin_bit_cast(h2, kwv[4*e+3]), qh[4*e+3], a3, false);
            }
            const int rel0 = kj / 6 - (qi >> 2) + 3;
            const int rel1 = kj % 6 - (qi & 3) + 3;
            sc[kj] = ((a0 + a1) + (a2 + a3)) * 0.17677669529f + rpb[(rel0 * 9 + rel1) * 6 + h];
        }
        float mx = -1e30f;
        #pragma unroll
        for (int kj = 0; kj < 36; ++kj) mx = fmaxf(mx, sc[kj]);
        float sum = 0.f;
        #pragma unroll
        for (int kj = 0; kj < 36; ++kj) { sc[kj] = __expf(sc[kj] - mx); sum += sc[kj]; }
        const float inv = 1.f / sum;

        // PV with packed f16 FMA
        h2 o2[16];
        #pragma unroll
        for (int e = 0; e < 16; ++e) o2[e] = (h2){ (_Float16)0.f, (_Float16)0.f };
        const short* vhb = vh + h * HSTR;
        #pragma unroll
        for (int kj = 0; kj < 36; ++kj) {
            const uint4* vp = (const uint4*)(vhb + kj * 32);
            uint4 v0 = vp[0], v1 = vp[1], v2 = vp[2], v3 = vp[3];
            unsigned vwv[16] = { v0.x, v0.y, v0.z, v0.w, v1.x, v1.y, v1.z, v1.w,
                                 v2.x, v2.y, v2.z, v2.w, v3.x, v3.y, v3.z, v3.w };
            const _Float16 ph = (_Float16)sc[kj];
            const h2 ph2 = { ph, ph };
            #pragma unroll
            for (int e = 0; e < 16; ++e)
                o2[e] = __builtin_bit_cast(h2, vwv[e]) * ph2 + o2[e];
        }
        bf16* op = out + ((size_t)(b * TOKPB + qr * CW + qc)) * 192 + h * 32;
        #pragma unroll
        for (int u = 0; u < 8; ++u) {
            s4v pk;
            #pragma unroll
            for (int e = 0; e < 2; ++e) {
                h2 ov = o2[u * 2 + e];
                pk[2 * e]     = (short)f2bf((float)ov[0] * inv);
                pk[2 * e + 1] = (short)f2bf((float)ov[1] * inv);
            }
            *(s4v*)((bf16*)op + u * 4) = pk;
        }
    }
}

// ---------------- final: out = relu(C2 + conv1x1(x)), MFMA ----------------
__global__ __launch_bounds__(256, 4) void final_mfma_kernel(
    const float* __restrict__ x, const short* __restrict__ w3f,
    const float* __restrict__ b3, const bf16* __restrict__ c2,
    float* __restrict__ out)
{
    __shared__ short xs2[12288];      // [64 pix][192 ci] bf16, row-swizzled
    const int pix0 = blockIdx.x * 64;
    const int b    = blockIdx.y;
    const int tid = threadIdx.x, lane = tid & 63, wid = tid >> 6;
    const int cl = lane & 15, kg = lane >> 4;
    const float* xb = x + (size_t)b * (192 * TOKPB);

    #pragma unroll
    for (int u = 0; u < 12; ++u) {
        int idx = u * 256 + tid;                  // 3072 float4
        int ci = idx >> 4, p4 = (idx & 15) << 2;
        float4 v = *(const float4*)(xb + (size_t)ci * TOKPB + pix0 + p4);
        float vv[4] = { v.x, v.y, v.z, v.w };
        #pragma unroll
        for (int k = 0; k < 4; ++k) {
            int row = p4 + k;
            int ba = (row * 384 + ci * 2) ^ ((row & 7) << 4);
            *(short*)((char*)xs2 + ba) = (short)f2bf(vv[k]);
        }
    }
    __syncthreads();

    const int ctb = wid * 3;
    f32x4 acc[3][4] = {};
    const s8v* wf8 = (const s8v*)w3f;

    #pragma unroll
    for (int kt = 0; kt < 6; ++kt) {
        s8v a0 = wf8[(size_t)(kt * 12 + ctb + 0) * 64 + lane];
        s8v a1 = wf8[(size_t)(kt * 12 + ctb + 1) * 64 + lane];
        s8v a2 = wf8[(size_t)(kt * 12 + ctb + 2) * 64 + lane];
        #pragma unroll
        for (int pt = 0; pt < 4; ++pt) {
            int row = pt * 16 + cl;
            int ba = (row * 384 + kt * 64 + kg * 16) ^ ((row & 7) << 4);
            s8v bfr = *(const s8v*)((const char*)xs2 + ba);
            acc[0][pt] = __builtin_amdgcn_mfma_f32_16x16x32_bf16(a0, bfr, acc[0][pt], 0, 0, 0);
            acc[1][pt] = __builtin_amdgcn_mfma_f32_16x16x32_bf16(a1, bfr, acc[1][pt], 0, 0, 0);
            acc[2][pt] = __builtin_amdgcn_mfma_f32_16x16x32_bf16(a2, bfr, acc[2][pt], 0, 0, 0);
        }
    }

    #pragma unroll
    for (int t = 0; t < 3; ++t) {
        #pragma unroll
        for (int r = 0; r < 4; ++r) {
            const int co = (ctb + t) * 16 + kg * 4 + r;
            const float bb = b3[co];
            const size_t rowbase = (size_t)b * (192 * TOKPB) + (size_t)co * TOKPB + pix0;
            #pragma unroll
            for (int pt = 0; pt < 4; ++pt) {
                const size_t f = rowbase + pt * 16 + cl;
                float v = acc[t][pt][r] + bb + bf2f(__builtin_bit_cast(short, c2[f]));
                out[f] = fmaxf(v, 0.f);
            }
        }
    }
}

// ---------------- host launch ----------------
extern "C" void kernel_launch(void* const* d_in, const int* in_sizes, int n_in,
                              void* d_out, int out_size, void* d_ws, size_t ws_size,
                              hipStream_t stream)
{
    if (ws_size < WS_NEEDED) return;

    const float* x       = (const float*)d_in[0];
    const float* conv1_w = (const float*)d_in[1];
    const float* conv1_b = (const float*)d_in[2];
    const float* gn1_g   = (const float*)d_in[3];
    const float* gn1_b   = (const float*)d_in[4];
    const float* conv2_w = (const float*)d_in[5];
    const float* conv2_b = (const float*)d_in[6];
    const float* gn2_g   = (const float*)d_in[7];
    const float* gn2_b   = (const float*)d_in[8];
    const float* conv3_w = (const float*)d_in[9];
    const float* conv3_b = (const float*)d_in[10];
    const float* ln1_g   = (const float*)d_in[11];
    const float* ln1_b   = (const float*)d_in[12];
    const float* qkv_w   = (const float*)d_in[13];
    const float* qkv_b   = (const float*)d_in[14];
    const float* rpb     = (const float*)d_in[15];
    const float* proj_w  = (const float*)d_in[16];
    const float* proj_b  = (const float*)d_in[17];
    const float* ln2_g   = (const float*)d_in[18];
    const float* ln2_b   = (const float*)d_in[19];
    const float* fc1_w   = (const float*)d_in[20];
    const float* fc1_b   = (const float*)d_in[21];
    const float* fc2_w   = (const float*)d_in[22];
    const float* fc2_b   = (const float*)d_in[23];

    char* wsb = (char*)d_ws;
    bf16*  T0  = (bf16*)(wsb + B_T0);
    _Float16* QF = (_Float16*)(wsb + B_P2);   // Q/K/V f16 sections; later HID bf16
    bf16*  HID = (bf16*)(wsb + B_P2);
    bf16*  P3  = (bf16*)(wsb + B_P3);
    bf16*  P4  = (bf16*)(wsb + B_P4);
    short* WF1 = (short*)(wsb + B_WF1);
    short* WF2 = (short*)(wsb + B_WF2);
    short* W3F = (short*)(wsb + B_W3F);
    short* WQ  = (short*)(wsb + B_WQ);
    short* WP  = (short*)(wsb + B_WP);
    short* WG1 = (short*)(wsb + B_WG1);
    short* WG2 = (short*)(wsb + B_WG2);
    float* OUT = (float*)d_out;

    // weight prep
    build_wf_kernel<<<(331776 + 255) / 256, 256, 0, stream>>>(conv1_w, WF1);
    build_wf_kernel<<<(331776 + 255) / 256, 256, 0, stream>>>(conv2_w, WF2);
    build_w3f_kernel<<<(36864 + 255) / 256, 256, 0, stream>>>(conv3_w, W3F);
    build_wgemm_kernel<<<(110592 + 255) / 256, 256, 0, stream>>>(qkv_w, WQ, 192, 576);
    build_wgemm_kernel<<<(36864 + 255) / 256, 256, 0, stream>>>(proj_w, WP, 192, 192);
    build_wgemm_kernel<<<(73728 + 255) / 256, 256, 0, stream>>>(fc1_w, WG1, 192, 384);
    build_wgemm_kernel<<<(73728 + 255) / 256, 256, 0, stream>>>(fc2_w, WG2, 384, 192);

    // stage A: conv1 + gn1 + silu -> T0 (token layout, bf16)
    conv_mfma_kernel<true><<<NPATCH / 4, 256, 0, stream>>>(x, WF1, conv1_b, gn1_g, gn1_b, T0);
    // stage C: LN1 (fused) + qkv gemm -> QF/KF/VF (f16 head-major)
    gemm_mfma_kernel<_Float16, false, false, true, true><<<dim3(MTOK / 128, 9), 256, 0, stream>>>(
        T0, WQ, qkv_b, nullptr, QF, 192, 576, ln1_g, ln1_b);
    // stage D: attention -> P3 (ATT, bf16 token layout)
    attn_kernel<<<NPATCH, 128, 0, stream>>>(QF, rpb, P3);
    // stage E: proj + shortcut(T0) -> P4 (OMID)
    gemm_mfma_kernel<bf16, true, false, false, false><<<dim3(MTOK / 128, 3), 256, 0, stream>>>(
        P3, WP, proj_b, T0, P4, 192, 192, nullptr, nullptr);
    // stage G: LN2 (fused) + fc1 + gelu -> HID
    gemm_mfma_kernel<bf16, false, true, true, false><<<dim3(MTOK / 128, 6), 256, 0, stream>>>(
        P4, WG1, fc1_b, nullptr, HID, 192, 384, ln2_g, ln2_b);
    // stage H: fc2 + residual(OMID P4) -> P3 (OCAB, bf16 token layout)
    gemm_mfma_kernel<bf16, true, false, false, false><<<dim3(MTOK / 128, 3), 256, 0, stream>>>(
        HID, WG2, fc2_b, P4, P3, 384, 192, nullptr, nullptr);
    // stage I: conv2 + gn2 (reads P3 bf16 token layout) -> P4 (C2, bf16 patch-flat)
    conv_mfma_kernel<false><<<NPATCH / 4, 256, 0, stream>>>(P3, WF2, conv2_b, gn2_g, gn2_b, P4);
    // stage J: out = relu(C2 + conv1x1(x)) -> d_out, MFMA
    final_mfma_kernel<<<dim3(TOKPB / 64, CB), 256, 0, stream>>>(x, W3F, conv3_b, P4, OUT);
}